// Round 2
// baseline (4197.988 us; speedup 1.0000x reference)
//
#include <hip/hip_runtime.h>
#include <hip/hip_bf16.h>

// Problem constants (HybridTextClassifier)
// B=16, S=256, V=32000, E=256, H=8, L=2, FFN=1024, NC=4, DK=32, NQ=256

__device__ __forceinline__ unsigned short f2bf(float f) {
  unsigned u = __builtin_bit_cast(unsigned, f);
  u += 0x7fffu + ((u >> 16) & 1u);
  return (unsigned short)(u >> 16);
}
__device__ __forceinline__ float sigm(float x) { return 1.f / (1.f + expf(-x)); }

// v_dot2_f32_bf16: acc += a.x*b.x + a.y*b.y  (packed bf16 pairs in uint)
#define DOT2BF(acc, a, b) \
  asm("v_dot2_f32_bf16 %0, %1, %2, %0" : "+v"(acc) : "v"(a), "v"(b))

// ---------------- embedding gather ----------------
__global__ void embed_kernel(const int* __restrict__ x, const float* __restrict__ tab,
                             float* __restrict__ emb) {
  int tok = blockIdx.x, tid = threadIdx.x;
  emb[tok * 256 + tid] = tab[x[tok] * 256 + tid];
}

// ---------------- pack x-part of lstm_W: Wxp[d][g*256+q] = lstm_W[g][d][q], d<256 ----------------
__global__ void pack_wx_kernel(const float* __restrict__ lstmW, float* __restrict__ Wxp) {
  int i = blockIdx.x * 256 + threadIdx.x;  // < 256*1024
  int d = i >> 10, n = i & 1023;
  int g = n >> 8, q = n & 255;
  Wxp[i] = lstmW[(g * 512 + d) * 256 + q];
}

// ---- pack h-part of gates 0..2 as bf16 d-pairs for per-thread register storage ----
// Wreg[r*256+q], r = (gi*2+s)*64+i : pair (W[gi][s*128+2i][q], W[gi][s*128+2i+1][q])
__global__ void pack_wreg_kernel(const float* __restrict__ lstmW, unsigned* __restrict__ Wreg) {
  int idx = blockIdx.x * 256 + threadIdx.x;  // < 98304
  int q = idx & 255;
  int r = idx >> 8;
  int i = r & 63;
  int gs = r >> 6;
  int s = gs & 1, gi = gs >> 1;
  int d = s * 128 + 2 * i;
  unsigned lo = f2bf(lstmW[(gi * 512 + 256 + d) * 256 + q]);
  unsigned hi = f2bf(lstmW[(gi * 512 + 256 + d + 1) * 256 + q]);
  Wreg[idx] = lo | (hi << 16);
}

// ---- pack h-part of gate 3 as bf16 d-pairs for LDS: WLg[dp*256+q] ----
__global__ void pack_wl_kernel(const float* __restrict__ lstmW, unsigned* __restrict__ WLg) {
  int idx = blockIdx.x * 256 + threadIdx.x;  // < 32768
  int q = idx & 255, dp = idx >> 8;
  unsigned lo = f2bf(lstmW[(3 * 512 + 256 + 2 * dp) * 256 + q]);
  unsigned hi = f2bf(lstmW[(3 * 512 + 256 + 2 * dp + 1) * 256 + q]);
  WLg[idx] = lo | (hi << 16);
}

// ---------------- generic f32 GEMM: C[M,N] = A[M,K]*B[K,N] + bias[N], opt relu ----------------
__global__ void __launch_bounds__(256) gemm_f32(const float* __restrict__ A,
                                                const float* __restrict__ Bm,
                                                const float* __restrict__ bias,
                                                float* __restrict__ C,
                                                int M, int N, int K, int relu) {
  __shared__ float As[16][65];
  __shared__ float Bs[16][65];
  int tid = threadIdx.x;
  int bm = blockIdx.y * 64;
  int bn = blockIdx.x * 64;
  int tx = tid & 15;   // n dir
  int ty = tid >> 4;   // m dir
  float acc[4][4] = {};
  for (int k0 = 0; k0 < K; k0 += 16) {
#pragma unroll
    for (int i = tid; i < 64 * 16; i += 256) {
      int r = i >> 4, kk = i & 15;
      As[kk][r] = A[(bm + r) * K + k0 + kk];
    }
#pragma unroll
    for (int i = tid; i < 16 * 64; i += 256) {
      int kk = i >> 6, cc = i & 63;
      Bs[kk][cc] = Bm[(k0 + kk) * N + bn + cc];
    }
    __syncthreads();
#pragma unroll
    for (int kk = 0; kk < 16; ++kk) {
      float a[4], bb[4];
#pragma unroll
      for (int i = 0; i < 4; ++i) a[i] = As[kk][ty + 16 * i];
#pragma unroll
      for (int j = 0; j < 4; ++j) bb[j] = Bs[kk][tx + 16 * j];
#pragma unroll
      for (int i = 0; i < 4; ++i)
#pragma unroll
        for (int j = 0; j < 4; ++j) acc[i][j] += a[i] * bb[j];
    }
    __syncthreads();
  }
#pragma unroll
  for (int i = 0; i < 4; ++i) {
    int r = bm + ty + 16 * i;
#pragma unroll
    for (int j = 0; j < 4; ++j) {
      int cc = bn + tx + 16 * j;
      float vv = acc[i][j] + bias[cc];
      if (relu) vv = fmaxf(vv, 0.f);
      C[r * N + cc] = vv;
    }
  }
}

// ---------------- QLSTM: one block per batch, all comm intra-block ----------------
// 512 threads = 8 waves. Thread t: q = t&255, s = t>>8 (d-half).
// Each thread computes the s-half (128 d) of column q for all 4 gates:
//   gates 0..2 weights in registers (192 packed uints), gate 3 in LDS (128 KiB).
// Partials combined via LDS; thread t finalizes outputs t (gate s) and 512+t (gate s+2).
__global__ void __launch_bounds__(512, 2) lstm_kernel(const unsigned* __restrict__ Wreg,
                                                      const unsigned* __restrict__ WLg,
                                                      const float* __restrict__ lstmTh,
                                                      const float* __restrict__ xw,
                                                      float* __restrict__ hb) {
  extern __shared__ char smem[];
  unsigned* WL = (unsigned*)smem;               // [128][256] packed bf16 d-pairs (131072 B)
  float* part = (float*)(smem + 131072);        // [8][256]  (g*2+s, q)
  float* qv = part + 2048;                      // [1024]
  float* wtot = qv + 1024;                      // [16]  (wave, slot)
  unsigned* hp = (unsigned*)(wtot + 16);        // [128] packed bf16 h pairs

  const int t = threadIdx.x;
  const int b = blockIdx.x;
  const int q = t & 255;
  const int s = t >> 8;          // d-half: d in [s*128, s*128+128)
  const int lane = t & 63;
  const int w = t >> 6;          // wave 0..7
  const int hb64 = s << 6;       // dp base

  // stage gate-3 weights into LDS
  for (int j = t; j < 32768; j += 512) WL[j] = WLg[j];
  // load gates 0..2 half-columns into registers
  unsigned wreg[192];
#pragma unroll
  for (int j = 0; j < 192; ++j) {
    int gi = j >> 6, i = j & 63;
    wreg[j] = Wreg[(((gi << 1) + s) * 64 + i) * 256 + q];
  }
  const float thA = lstmTh[t];          // gate s, col q
  const float thB = lstmTh[512 + t];    // gate s+2, col q
  float cx = 0.f;                       // valid for t<256 (q-owner)
  if (t < 128) hp[t] = 0u;              // h0 = 0
  __syncthreads();

  const int xbase = (b << 8) * 1024;

  for (int st = 0; st < 256; ++st) {
    // issue xw loads early; consumed after the barrier (latency hidden under GEMV)
    float xa = xw[xbase + st * 1024 + t];
    float xb = xw[xbase + st * 1024 + 512 + t];

    // ---- GEMV half-dots: 4 gates, 128 d each (64 packed pairs) ----
    float a0 = 0.f, a1 = 0.f, a2 = 0.f, a3 = 0.f;
#pragma unroll
    for (int i = 0; i < 64; ++i) {
      unsigned hh = hp[hb64 + i];
      unsigned wl = WL[((hb64 + i) << 8) + q];
      DOT2BF(a0, wreg[i], hh);
      DOT2BF(a1, wreg[64 + i], hh);
      DOT2BF(a2, wreg[128 + i], hh);
      DOT2BF(a3, wl, hh);
    }
    part[(0 * 2 + s) * 256 + q] = a0;
    part[(1 * 2 + s) * 256 + q] = a1;
    part[(2 * 2 + s) * 256 + q] = a2;
    part[(3 * 2 + s) * 256 + q] = a3;
    __syncthreads();

    // ---- finalize z, cos ----
    int gA = s, gB = s + 2;
    float zA = part[(gA * 2 + 0) * 256 + q] + part[(gA * 2 + 1) * 256 + q] + xa + thA;
    float zB = part[(gB * 2 + 0) * 256 + q] + part[(gB * 2 + 1) * 256 + q] + xb + thB;
    float vA = cosf(zA);
    float vB = cosf(zB);

    // ---- cumprod scan along q (4 waves per gate), 2 slots in parallel ----
#pragma unroll
    for (int off = 1; off < 64; off <<= 1) {
      float oA = __shfl_up(vA, off, 64);
      float oB = __shfl_up(vB, off, 64);
      if (lane >= off) { vA *= oA; vB *= oB; }
    }
    if (lane == 63) { wtot[w * 2] = vA; wtot[w * 2 + 1] = vB; }
    __syncthreads();
    {
      float pA = 1.f, pB = 1.f;
      int w0 = w & ~3;
      for (int k = w0; k < w; ++k) { pA *= wtot[k * 2]; pB *= wtot[k * 2 + 1]; }
      vA *= pA;
      vB *= pB;
    }
    qv[t] = vA;        // gate s,   col q  (== output index t)
    qv[512 + t] = vB;  // gate s+2, col q
    __syncthreads();

    // ---- combine gates, update cx/h (threads 0..255 own q) ----
    if (t < 256) {
      float fg = sigm(qv[t]);
      float ig = sigm(qv[256 + t]);
      float gg = tanhf(qv[512 + t]);
      float og = sigm(qv[768 + t]);
      cx = fg * cx + ig * gg;
      float hv = og * tanhf(cx);
      hb[((b << 8) + st) * 256 + t] = hv;
      float nb = __shfl_xor(hv, 1, 64);
      if ((t & 1) == 0) hp[t >> 1] = (unsigned)f2bf(hv) | ((unsigned)f2bf(nb) << 16);
    }
    __syncthreads();
  }
}

// ---------------- h += sinusoidal PE ----------------
__global__ void pe_add_kernel(float* __restrict__ h) {
  int tok = blockIdx.x, tid = threadIdx.x;
  int s = tok & 255;
  int j = tid >> 1;
  float div = expf((float)j * -0.07195578415622253f);  // 2j * (-ln(10000)/256)
  float ang = (float)s * div;
  float pe = (tid & 1) ? cosf(ang) : sinf(ang);
  h[tok * 256 + tid] += pe;
}

// ---------------- qproj: out = cumprod(cos(h + theta)) along E ----------------
__global__ void qproj_kernel(const float* __restrict__ hin, const float* __restrict__ theta,
                             float* __restrict__ out) {
  __shared__ float wtot[4];
  int tok = blockIdx.x, tid = threadIdx.x, lane = tid & 63, wid = tid >> 6;
  float v = cosf(hin[tok * 256 + tid] + theta[tid]);
#pragma unroll
  for (int off = 1; off < 64; off <<= 1) {
    float o = __shfl_up(v, off, 64);
    if (lane >= off) v *= o;
  }
  if (lane == 63) wtot[wid] = v;
  __syncthreads();
  float pre = 1.f;
  for (int w = 0; w < wid; ++w) pre *= wtot[w];
  out[tok * 256 + tid] = v * pre;
}

// ---------------- attention: one block per (head, batch); wave-per-row ----------------
__global__ void __launch_bounds__(256, 1) attn_kernel(const float* __restrict__ qb,
                                                      const float* __restrict__ kb,
                                                      const float* __restrict__ vb,
                                                      float* __restrict__ attnout) {
  extern __shared__ float sm[];
  float* Qs = sm;                 // [256][33]
  float* Ks = Qs + 256 * 33;
  float* Vs = Ks + 256 * 33;
  float* ps = Vs + 256 * 33;      // [4][256]
  int hd = blockIdx.x, b = blockIdx.y;
  int tid = threadIdx.x, lane = tid & 63, wid = tid >> 6;
  const float scale = 0.17677669529663687f;  // 1/sqrt(32)

  for (int i = tid; i < 256 * 32; i += 256) {
    int r = i >> 5, d = i & 31;
    int src = (b * 256 + r) * 256 + hd * 32 + d;
    Qs[r * 33 + d] = qb[src];
    Ks[r * 33 + d] = kb[src];
    Vs[r * 33 + d] = vb[src];
  }
  __syncthreads();

  float* pw = ps + wid * 256;
  for (int r = wid; r < 256; r += 4) {
    float qreg[32];
#pragma unroll
    for (int d = 0; d < 32; ++d) qreg[d] = Qs[r * 33 + d];
    float s[4];
#pragma unroll
    for (int j = 0; j < 4; ++j) {
      int k = lane + 64 * j;
      float a = 0.f;
#pragma unroll
      for (int d = 0; d < 32; ++d) a += qreg[d] * Ks[k * 33 + d];
      s[j] = a * scale;
    }
    float m = fmaxf(fmaxf(s[0], s[1]), fmaxf(s[2], s[3]));
#pragma unroll
    for (int off = 32; off; off >>= 1) m = fmaxf(m, __shfl_xor(m, off, 64));
    float p[4], sum = 0.f;
#pragma unroll
    for (int j = 0; j < 4; ++j) { p[j] = expf(s[j] - m); sum += p[j]; }
#pragma unroll
    for (int off = 32; off; off >>= 1) sum += __shfl_xor(sum, off, 64);
    float inv = 1.f / sum;
#pragma unroll
    for (int j = 0; j < 4; ++j) pw[lane + 64 * j] = p[j] * inv;
    int d = lane & 31, half = lane >> 5;
    float a = 0.f;
#pragma unroll 8
    for (int i2 = 0; i2 < 128; ++i2) {
      int k = half * 128 + i2;
      a += pw[k] * Vs[k * 33 + d];
    }
    a += __shfl_down(a, 32, 64);
    if (lane < 32) attnout[(b * 256 + r) * 256 + hd * 32 + d] = a;
  }
}

// ---------------- layernorm(h + delta) -> h ----------------
__global__ void ln_kernel(float* __restrict__ hio, const float* __restrict__ delta,
                          const float* __restrict__ gamma, const float* __restrict__ beta) {
  __shared__ float red[16];
  int tok = blockIdx.x, tid = threadIdx.x, lane = tid & 63, wid = tid >> 6;
  float v = hio[tok * 256 + tid] + delta[tok * 256 + tid];
  float s1 = v, s2 = v * v;
#pragma unroll
  for (int off = 32; off; off >>= 1) {
    s1 += __shfl_xor(s1, off, 64);
    s2 += __shfl_xor(s2, off, 64);
  }
  if (lane == 0) { red[wid] = s1; red[wid + 8] = s2; }
  __syncthreads();
  float t1 = red[0] + red[1] + red[2] + red[3];
  float t2 = red[8] + red[9] + red[10] + red[11];
  float mean = t1 * (1.f / 256.f);
  float var = t2 * (1.f / 256.f) - mean * mean;
  float w = rsqrtf(var + 1e-5f);
  hio[tok * 256 + tid] = (v - mean) * w * gamma[tid] + beta[tid];
}

// ---------------- mean pool over S + classifier ----------------
__global__ void pool_cls_kernel(const float* __restrict__ h, const float* __restrict__ clsW,
                                const float* __restrict__ clsb, float* __restrict__ out) {
  __shared__ float pl[256];
  __shared__ float red[8];
  int b = blockIdx.x, tid = threadIdx.x, lane = tid & 63, wid = tid >> 6;
  float s = 0.f;
  for (int t = 0; t < 256; ++t) s += h[(b * 256 + t) * 256 + tid];
  pl[tid] = s * (1.f / 256.f);
  __syncthreads();
  for (int c = 0; c < 4; ++c) {
    float v = pl[tid] * clsW[tid * 4 + c];
#pragma unroll
    for (int off = 32; off; off >>= 1) v += __shfl_xor(v, off, 64);
    if (lane == 0) red[wid] = v;
    __syncthreads();
    if (tid == 0) out[b * 4 + c] = red[0] + red[1] + red[2] + red[3] + clsb[c];
    __syncthreads();
  }
}

extern "C" void kernel_launch(void* const* d_in, const int* in_sizes, int n_in,
                              void* d_out, int out_size, void* d_ws, size_t ws_size,
                              hipStream_t stream) {
  const int* x = (const int*)d_in[0];
  const float* token_emb = (const float*)d_in[1];
  const float* lstm_W = (const float*)d_in[2];
  const float* lstm_b = (const float*)d_in[3];
  const float* lstm_th = (const float*)d_in[4];
  const float* ln1_g = (const float*)d_in[5];
  const float* ln1_b = (const float*)d_in[6];
  const float* ln2_g = (const float*)d_in[7];
  const float* ln2_b = (const float*)d_in[8];
  const float* qkv_th = (const float*)d_in[9];
  const float* comb_W = (const float*)d_in[10];
  const float* comb_b = (const float*)d_in[11];
  const float* ffn_th = (const float*)d_in[12];
  const float* lin1_W = (const float*)d_in[13];
  const float* lin1_b = (const float*)d_in[14];
  const float* lin2_W = (const float*)d_in[15];
  const float* lin2_b = (const float*)d_in[16];
  const float* cls_W = (const float*)d_in[17];
  const float* cls_b = (const float*)d_in[18];

  float* ws = (float*)d_ws;
  float* emb = ws;                       // 1M floats (later: attnout)
  float* xw = ws + 1048576;              // 4M (later: ffh)
  float* hb = ws + 5242880;              // 1M
  float* qq = ws + 6291456;              // 1M
  float* kk = ws + 7340032;              // 1M
  float* vv = ws + 8388608;              // 1M (later: ffq)
  float* tmp = ws + 9437184;             // 1M floats; first 131072 reused BEFORE the
                                         // transformer loop as packed LSTM weights
  float* Wxp = ws + 10485760;            // 256K

  unsigned* Wreg = (unsigned*)tmp;              // 98304 uints (gates 0..2 packed)
  unsigned* WLg = (unsigned*)(tmp + 98304);     // 32768 uints (gate 3 packed)

  const int LSTM_LDS = 131072 + 8192 + 4096 + 64 + 512;       // 143936 B
  const int ATT_LDS = (3 * 256 * 33 + 4 * 256) * 4;           // 105472 B
  (void)hipFuncSetAttribute(reinterpret_cast<const void*>(lstm_kernel),
                            hipFuncAttributeMaxDynamicSharedMemorySize, LSTM_LDS);
  (void)hipFuncSetAttribute(reinterpret_cast<const void*>(attn_kernel),
                            hipFuncAttributeMaxDynamicSharedMemorySize, ATT_LDS);

  embed_kernel<<<4096, 256, 0, stream>>>(x, token_emb, emb);
  pack_wx_kernel<<<1024, 256, 0, stream>>>(lstm_W, Wxp);
  pack_wreg_kernel<<<384, 256, 0, stream>>>(lstm_W, Wreg);
  pack_wl_kernel<<<128, 256, 0, stream>>>(lstm_W, WLg);
  // xw[token][g*256+q] = emb . Wx + lstm_b
  gemm_f32<<<dim3(16, 64), 256, 0, stream>>>(emb, Wxp, lstm_b, xw, 4096, 1024, 256, 0);
  lstm_kernel<<<16, 512, LSTM_LDS, stream>>>(Wreg, WLg, lstm_th, xw, hb);
  pe_add_kernel<<<4096, 256, 0, stream>>>(hb);

  for (int l = 0; l < 2; ++l) {
    qproj_kernel<<<4096, 256, 0, stream>>>(hb, qkv_th + (l * 3 + 0) * 256, qq);
    qproj_kernel<<<4096, 256, 0, stream>>>(hb, qkv_th + (l * 3 + 1) * 256, kk);
    qproj_kernel<<<4096, 256, 0, stream>>>(hb, qkv_th + (l * 3 + 2) * 256, vv);
    attn_kernel<<<dim3(8, 16), 256, ATT_LDS, stream>>>(qq, kk, vv, emb);
    gemm_f32<<<dim3(4, 64), 256, 0, stream>>>(emb, comb_W + l * 65536, comb_b + l * 256,
                                              tmp, 4096, 256, 256, 0);
    ln_kernel<<<4096, 256, 0, stream>>>(hb, tmp, ln1_g + l * 256, ln1_b + l * 256);
    qproj_kernel<<<4096, 256, 0, stream>>>(hb, ffn_th + l * 256, vv);
    gemm_f32<<<dim3(16, 64), 256, 0, stream>>>(vv, lin1_W + l * 262144, lin1_b + l * 1024,
                                               xw, 4096, 1024, 256, 1);
    gemm_f32<<<dim3(4, 64), 256, 0, stream>>>(xw, lin2_W + l * 262144, lin2_b + l * 256,
                                              tmp, 4096, 256, 1024, 0);
    ln_kernel<<<4096, 256, 0, stream>>>(hb, tmp, ln2_g + l * 256, ln2_b + l * 256);
  }

  pool_cls_kernel<<<16, 256, 0, stream>>>(hb, cls_W, cls_b, (float*)d_out);
}

// Round 3
// 1726.181 us; speedup vs baseline: 2.4320x; 2.4320x over previous
//
#include <hip/hip_runtime.h>
#include <hip/hip_bf16.h>

// Problem constants (HybridTextClassifier)
// B=16, S=256, V=32000, E=256, H=8, L=2, FFN=1024, NC=4, DK=32, NQ=256

__device__ __forceinline__ unsigned short f2bf(float f) {
  unsigned u = __builtin_bit_cast(unsigned, f);
  u += 0x7fffu + ((u >> 16) & 1u);
  return (unsigned short)(u >> 16);
}
__device__ __forceinline__ float rcp_f(float x) { return __builtin_amdgcn_rcpf(x); }
__device__ __forceinline__ float sigm(float x) { return rcp_f(1.f + __expf(-x)); }
__device__ __forceinline__ float tanh_f(float x) { return 1.f - 2.f * rcp_f(__expf(2.f * x) + 1.f); }

// v_dot2_f32_bf16: acc += a.x*b.x + a.y*b.y  (packed bf16 pairs in uint)
#define DOT2BF(acc, a, b) \
  asm("v_dot2_f32_bf16 %0, %1, %2, %0" : "+v"(acc) : "v"(a), "v"(b))

// ---------------- embedding gather ----------------
__global__ void embed_kernel(const int* __restrict__ x, const float* __restrict__ tab,
                             float* __restrict__ emb) {
  int tok = blockIdx.x, tid = threadIdx.x;
  emb[tok * 256 + tid] = tab[x[tok] * 256 + tid];
}

// ---------------- pack x-part of lstm_W: Wxp[d][g*256+q] = lstm_W[g][d][q], d<256 ----------------
__global__ void pack_wx_kernel(const float* __restrict__ lstmW, float* __restrict__ Wxp) {
  int i = blockIdx.x * 256 + threadIdx.x;  // < 256*1024
  int d = i >> 10, n = i & 1023;
  int g = n >> 8, q = n & 255;
  Wxp[i] = lstmW[(g * 512 + d) * 256 + q];
}

// ---- pack h-part of gates 0..2 as bf16 d-pairs, uint4-friendly layout ----
// uint index o = ((gs*16 + i4)*256 + q)*4 + c ; gs=gi*2+s, pair i=i4*4+c, d=s*128+2i
__global__ void pack_wreg_kernel(const float* __restrict__ lstmW, unsigned* __restrict__ Wreg) {
  int o = blockIdx.x * 256 + threadIdx.x;  // < 98304
  int c = o & 3;
  int q = (o >> 2) & 255;
  int i4 = (o >> 10) & 15;
  int gs = o >> 14;  // 0..5
  int gi = gs >> 1, s = gs & 1;
  int i = i4 * 4 + c;
  int d = s * 128 + 2 * i;
  unsigned lo = f2bf(lstmW[(gi * 512 + 256 + d) * 256 + q]);
  unsigned hi = f2bf(lstmW[(gi * 512 + 256 + d + 1) * 256 + q]);
  Wreg[o] = lo | (hi << 16);
}

// ---- pack h-part of gate 3 as bf16 d-pairs for LDS, uint4-friendly ----
// uint index o = (p4*256 + q)*4 + c ; pair p=p4*4+c, d=2p
__global__ void pack_wl_kernel(const float* __restrict__ lstmW, unsigned* __restrict__ WLg) {
  int o = blockIdx.x * 256 + threadIdx.x;  // < 32768
  int c = o & 3;
  int q = (o >> 2) & 255;
  int p4 = o >> 10;  // 0..31
  int d = 2 * (p4 * 4 + c);
  unsigned lo = f2bf(lstmW[(3 * 512 + 256 + d) * 256 + q]);
  unsigned hi = f2bf(lstmW[(3 * 512 + 256 + d + 1) * 256 + q]);
  WLg[o] = lo | (hi << 16);
}

// ---------------- generic f32 GEMM: C[M,N] = A[M,K]*B[K,N] + bias[N], opt relu ----------------
__global__ void __launch_bounds__(256) gemm_f32(const float* __restrict__ A,
                                                const float* __restrict__ Bm,
                                                const float* __restrict__ bias,
                                                float* __restrict__ C,
                                                int M, int N, int K, int relu) {
  __shared__ float As[16][65];
  __shared__ float Bs[16][65];
  int tid = threadIdx.x;
  int bm = blockIdx.y * 64;
  int bn = blockIdx.x * 64;
  int tx = tid & 15;   // n dir
  int ty = tid >> 4;   // m dir
  float acc[4][4] = {};
  for (int k0 = 0; k0 < K; k0 += 16) {
#pragma unroll
    for (int i = tid; i < 64 * 16; i += 256) {
      int r = i >> 4, kk = i & 15;
      As[kk][r] = A[(bm + r) * K + k0 + kk];
    }
#pragma unroll
    for (int i = tid; i < 16 * 64; i += 256) {
      int kk = i >> 6, cc = i & 63;
      Bs[kk][cc] = Bm[(k0 + kk) * N + bn + cc];
    }
    __syncthreads();
#pragma unroll
    for (int kk = 0; kk < 16; ++kk) {
      float a[4], bb[4];
#pragma unroll
      for (int i = 0; i < 4; ++i) a[i] = As[kk][ty + 16 * i];
#pragma unroll
      for (int j = 0; j < 4; ++j) bb[j] = Bs[kk][tx + 16 * j];
#pragma unroll
      for (int i = 0; i < 4; ++i)
#pragma unroll
        for (int j = 0; j < 4; ++j) acc[i][j] += a[i] * bb[j];
    }
    __syncthreads();
  }
#pragma unroll
  for (int i = 0; i < 4; ++i) {
    int r = bm + ty + 16 * i;
#pragma unroll
    for (int j = 0; j < 4; ++j) {
      int cc = bn + tx + 16 * j;
      float vv = acc[i][j] + bias[cc];
      if (relu) vv = fmaxf(vv, 0.f);
      C[r * N + cc] = vv;
    }
  }
}

// ---------------- QLSTM: one block per batch, all comm intra-block ----------------
// 512 threads. Thread t: q = t&255, s = t>>8 (d-half of 128).
// Gates 0..2 weights in 48 uint4 registers; gate 3 in LDS (128 KiB, b128 reads).
__global__ void __launch_bounds__(512, 2) lstm_kernel(const unsigned* __restrict__ Wreg,
                                                      const unsigned* __restrict__ WLg,
                                                      const float* __restrict__ lstmTh,
                                                      const float* __restrict__ xw,
                                                      float* __restrict__ hb) {
  extern __shared__ char smem[];
  unsigned* WL = (unsigned*)smem;               // [32][256] uint4 rows (131072 B)
  float* part = (float*)(smem + 131072);        // [8][256]  (g*2+s, q)
  float* qv = part + 2048;                      // [1024]
  float* wtot = qv + 1024;                      // [16]  (wave, slot)
  unsigned* hp = (unsigned*)(wtot + 16);        // [128] packed bf16 h pairs (16B aligned)

  const int t = threadIdx.x;
  const int b = blockIdx.x;
  const int q = t & 255;
  const int s = t >> 8;          // d-half: d in [s*128, s*128+128)
  const int lane = t & 63;
  const int w = t >> 6;          // wave 0..7

  // stage gate-3 weights into LDS (b128 copies)
  {
    const uint4* src = (const uint4*)WLg;
    uint4* dst = (uint4*)WL;
    for (int j = t; j < 8192; j += 512) dst[j] = src[j];
  }
  // load gates 0..2 half-columns into registers (48 dwordx4 loads)
  const uint4* Wreg4 = (const uint4*)Wreg;
  uint4 wreg[48];
#pragma unroll
  for (int j = 0; j < 48; ++j) {
    int gi = j >> 4, i4 = j & 15;
    wreg[j] = Wreg4[((gi * 2 + s) * 16 + i4) * 256 + q];
  }
  const float thA = lstmTh[t];          // gate s, col q
  const float thB = lstmTh[512 + t];    // gate s+2, col q
  float cx = 0.f;                       // valid for t<256 (q-owner)
  if (t < 128) hp[t] = 0u;              // h0 = 0
  __syncthreads();

  const int xbase = (b << 8) * 1024;
  const uint4* WL4 = (const uint4*)WL;
  const uint4* hp4 = (const uint4*)hp;

  for (int st = 0; st < 256; ++st) {
    // issue xw loads early; consumed after the barrier (latency hidden under GEMV)
    float xa = xw[xbase + st * 1024 + t];
    float xb = xw[xbase + st * 1024 + 512 + t];

    // ---- GEMV half-dots: 4 gates, 128 d each (64 packed pairs = 16 uint4) ----
    float a0 = 0.f, a1 = 0.f, a2 = 0.f, a3 = 0.f;
#pragma unroll
    for (int i4 = 0; i4 < 16; ++i4) {
      uint4 hh = hp4[(s << 4) + i4];                 // broadcast b128
      uint4 w3 = WL4[((s << 4) + i4) * 256 + q];     // coalesced b128
      uint4 w0 = wreg[i4];
      uint4 w1 = wreg[16 + i4];
      uint4 w2 = wreg[32 + i4];
      DOT2BF(a0, w0.x, hh.x); DOT2BF(a0, w0.y, hh.y);
      DOT2BF(a0, w0.z, hh.z); DOT2BF(a0, w0.w, hh.w);
      DOT2BF(a1, w1.x, hh.x); DOT2BF(a1, w1.y, hh.y);
      DOT2BF(a1, w1.z, hh.z); DOT2BF(a1, w1.w, hh.w);
      DOT2BF(a2, w2.x, hh.x); DOT2BF(a2, w2.y, hh.y);
      DOT2BF(a2, w2.z, hh.z); DOT2BF(a2, w2.w, hh.w);
      DOT2BF(a3, w3.x, hh.x); DOT2BF(a3, w3.y, hh.y);
      DOT2BF(a3, w3.z, hh.z); DOT2BF(a3, w3.w, hh.w);
    }
    part[(0 * 2 + s) * 256 + q] = a0;
    part[(1 * 2 + s) * 256 + q] = a1;
    part[(2 * 2 + s) * 256 + q] = a2;
    part[(3 * 2 + s) * 256 + q] = a3;
    __syncthreads();

    // ---- finalize z, cos (native, branch-free) ----
    int gA = s, gB = s + 2;
    float zA = part[(gA * 2 + 0) * 256 + q] + part[(gA * 2 + 1) * 256 + q] + xa + thA;
    float zB = part[(gB * 2 + 0) * 256 + q] + part[(gB * 2 + 1) * 256 + q] + xb + thB;
    float vA = __cosf(zA);
    float vB = __cosf(zB);

    // ---- cumprod scan along q (4 waves per gate), 2 slots in parallel ----
#pragma unroll
    for (int off = 1; off < 64; off <<= 1) {
      float oA = __shfl_up(vA, off, 64);
      float oB = __shfl_up(vB, off, 64);
      if (lane >= off) { vA *= oA; vB *= oB; }
    }
    if (lane == 63) { wtot[w * 2] = vA; wtot[w * 2 + 1] = vB; }
    __syncthreads();
    {
      float pA = 1.f, pB = 1.f;
      int w0 = w & ~3;
      for (int k = w0; k < w; ++k) { pA *= wtot[k * 2]; pB *= wtot[k * 2 + 1]; }
      vA *= pA;
      vB *= pB;
    }
    qv[t] = vA;        // gate s,   col q  (== output index t)
    qv[512 + t] = vB;  // gate s+2, col q
    __syncthreads();

    // ---- combine gates, update cx/h (threads 0..255 own q) ----
    if (t < 256) {
      float fg = sigm(qv[t]);
      float ig = sigm(qv[256 + t]);
      float gg = tanh_f(qv[512 + t]);
      float og = sigm(qv[768 + t]);
      cx = fg * cx + ig * gg;
      float hv = og * tanh_f(cx);
      hb[((b << 8) + st) * 256 + t] = hv;
      float nb = __shfl_xor(hv, 1, 64);
      if ((t & 1) == 0) hp[t >> 1] = (unsigned)f2bf(hv) | ((unsigned)f2bf(nb) << 16);
    }
    __syncthreads();
  }
}

// ---------------- h += sinusoidal PE ----------------
__global__ void pe_add_kernel(float* __restrict__ h) {
  int tok = blockIdx.x, tid = threadIdx.x;
  int s = tok & 255;
  int j = tid >> 1;
  float div = __expf((float)j * -0.07195578415622253f);  // 2j * (-ln(10000)/256)
  float ang = (float)s * div;
  float pe = (tid & 1) ? __cosf(ang) : __sinf(ang);
  h[tok * 256 + tid] += pe;
}

// ---------------- qproj: out = cumprod(cos(h + theta)) along E ----------------
__global__ void qproj_kernel(const float* __restrict__ hin, const float* __restrict__ theta,
                             float* __restrict__ out) {
  __shared__ float wtot[4];
  int tok = blockIdx.x, tid = threadIdx.x, lane = tid & 63, wid = tid >> 6;
  float v = __cosf(hin[tok * 256 + tid] + theta[tid]);
#pragma unroll
  for (int off = 1; off < 64; off <<= 1) {
    float o = __shfl_up(v, off, 64);
    if (lane >= off) v *= o;
  }
  if (lane == 63) wtot[wid] = v;
  __syncthreads();
  float pre = 1.f;
  for (int w = 0; w < wid; ++w) pre *= wtot[w];
  out[tok * 256 + tid] = v * pre;
}

// ---------------- attention: one block per (head, batch); wave-per-row ----------------
__global__ void __launch_bounds__(256, 1) attn_kernel(const float* __restrict__ qb,
                                                      const float* __restrict__ kb,
                                                      const float* __restrict__ vb,
                                                      float* __restrict__ attnout) {
  extern __shared__ float sm[];
  float* Qs = sm;                 // [256][33]
  float* Ks = Qs + 256 * 33;
  float* Vs = Ks + 256 * 33;
  float* ps = Vs + 256 * 33;      // [4][256]
  int hd = blockIdx.x, b = blockIdx.y;
  int tid = threadIdx.x, lane = tid & 63, wid = tid >> 6;
  const float scale = 0.17677669529663687f;  // 1/sqrt(32)

  for (int i = tid; i < 256 * 32; i += 256) {
    int r = i >> 5, d = i & 31;
    int src = (b * 256 + r) * 256 + hd * 32 + d;
    Qs[r * 33 + d] = qb[src];
    Ks[r * 33 + d] = kb[src];
    Vs[r * 33 + d] = vb[src];
  }
  __syncthreads();

  float* pw = ps + wid * 256;
  for (int r = wid; r < 256; r += 4) {
    float qreg[32];
#pragma unroll
    for (int d = 0; d < 32; ++d) qreg[d] = Qs[r * 33 + d];
    float s[4];
#pragma unroll
    for (int j = 0; j < 4; ++j) {
      int k = lane + 64 * j;
      float a = 0.f;
#pragma unroll
      for (int d = 0; d < 32; ++d) a += qreg[d] * Ks[k * 33 + d];
      s[j] = a * scale;
    }
    float m = fmaxf(fmaxf(s[0], s[1]), fmaxf(s[2], s[3]));
#pragma unroll
    for (int off = 32; off; off >>= 1) m = fmaxf(m, __shfl_xor(m, off, 64));
    float p[4], sum = 0.f;
#pragma unroll
    for (int j = 0; j < 4; ++j) { p[j] = __expf(s[j] - m); sum += p[j]; }
#pragma unroll
    for (int off = 32; off; off >>= 1) sum += __shfl_xor(sum, off, 64);
    float inv = rcp_f(sum);
#pragma unroll
    for (int j = 0; j < 4; ++j) pw[lane + 64 * j] = p[j] * inv;
    int d = lane & 31, half = lane >> 5;
    float a = 0.f;
#pragma unroll 8
    for (int i2 = 0; i2 < 128; ++i2) {
      int k = half * 128 + i2;
      a += pw[k] * Vs[k * 33 + d];
    }
    a += __shfl_down(a, 32, 64);
    if (lane < 32) attnout[(b * 256 + r) * 256 + hd * 32 + d] = a;
  }
}

// ---------------- layernorm(h + delta) -> h ----------------
__global__ void ln_kernel(float* __restrict__ hio, const float* __restrict__ delta,
                          const float* __restrict__ gamma, const float* __restrict__ beta) {
  __shared__ float red[16];
  int tok = blockIdx.x, tid = threadIdx.x, lane = tid & 63, wid = tid >> 6;
  float v = hio[tok * 256 + tid] + delta[tok * 256 + tid];
  float s1 = v, s2 = v * v;
#pragma unroll
  for (int off = 32; off; off >>= 1) {
    s1 += __shfl_xor(s1, off, 64);
    s2 += __shfl_xor(s2, off, 64);
  }
  if (lane == 0) { red[wid] = s1; red[wid + 8] = s2; }
  __syncthreads();
  float t1 = red[0] + red[1] + red[2] + red[3];
  float t2 = red[8] + red[9] + red[10] + red[11];
  float mean = t1 * (1.f / 256.f);
  float var = t2 * (1.f / 256.f) - mean * mean;
  float w = rsqrtf(var + 1e-5f);
  hio[tok * 256 + tid] = (v - mean) * w * gamma[tid] + beta[tid];
}

// ---------------- mean pool over S + classifier ----------------
__global__ void pool_cls_kernel(const float* __restrict__ h, const float* __restrict__ clsW,
                                const float* __restrict__ clsb, float* __restrict__ out) {
  __shared__ float pl[256];
  __shared__ float red[8];
  int b = blockIdx.x, tid = threadIdx.x, lane = tid & 63, wid = tid >> 6;
  float s = 0.f;
  for (int t = 0; t < 256; ++t) s += h[(b * 256 + t) * 256 + tid];
  pl[tid] = s * (1.f / 256.f);
  __syncthreads();
  for (int c = 0; c < 4; ++c) {
    float v = pl[tid] * clsW[tid * 4 + c];
#pragma unroll
    for (int off = 32; off; off >>= 1) v += __shfl_xor(v, off, 64);
    if (lane == 0) red[wid] = v;
    __syncthreads();
    if (tid == 0) out[b * 4 + c] = red[0] + red[1] + red[2] + red[3] + clsb[c];
    __syncthreads();
  }
}

extern "C" void kernel_launch(void* const* d_in, const int* in_sizes, int n_in,
                              void* d_out, int out_size, void* d_ws, size_t ws_size,
                              hipStream_t stream) {
  const int* x = (const int*)d_in[0];
  const float* token_emb = (const float*)d_in[1];
  const float* lstm_W = (const float*)d_in[2];
  const float* lstm_b = (const float*)d_in[3];
  const float* lstm_th = (const float*)d_in[4];
  const float* ln1_g = (const float*)d_in[5];
  const float* ln1_b = (const float*)d_in[6];
  const float* ln2_g = (const float*)d_in[7];
  const float* ln2_b = (const float*)d_in[8];
  const float* qkv_th = (const float*)d_in[9];
  const float* comb_W = (const float*)d_in[10];
  const float* comb_b = (const float*)d_in[11];
  const float* ffn_th = (const float*)d_in[12];
  const float* lin1_W = (const float*)d_in[13];
  const float* lin1_b = (const float*)d_in[14];
  const float* lin2_W = (const float*)d_in[15];
  const float* lin2_b = (const float*)d_in[16];
  const float* cls_W = (const float*)d_in[17];
  const float* cls_b = (const float*)d_in[18];

  float* ws = (float*)d_ws;
  float* emb = ws;                       // 1M floats (later: attnout)
  float* xw = ws + 1048576;              // 4M (later: ffh)
  float* hb = ws + 5242880;              // 1M
  float* qq = ws + 6291456;              // 1M
  float* kk = ws + 7340032;              // 1M
  float* vv = ws + 8388608;              // 1M (later: ffq)
  float* tmp = ws + 9437184;             // 1M floats; first 131072 reused BEFORE the
                                         // transformer loop as packed LSTM weights
  float* Wxp = ws + 10485760;            // 256K

  unsigned* Wreg = (unsigned*)tmp;              // 98304 uints (gates 0..2 packed)
  unsigned* WLg = (unsigned*)(tmp + 98304);     // 32768 uints (gate 3 packed)

  const int LSTM_LDS = 131072 + 8192 + 4096 + 64 + 512;       // 143936 B
  const int ATT_LDS = (3 * 256 * 33 + 4 * 256) * 4;           // 105472 B
  (void)hipFuncSetAttribute(reinterpret_cast<const void*>(lstm_kernel),
                            hipFuncAttributeMaxDynamicSharedMemorySize, LSTM_LDS);
  (void)hipFuncSetAttribute(reinterpret_cast<const void*>(attn_kernel),
                            hipFuncAttributeMaxDynamicSharedMemorySize, ATT_LDS);

  embed_kernel<<<4096, 256, 0, stream>>>(x, token_emb, emb);
  pack_wx_kernel<<<1024, 256, 0, stream>>>(lstm_W, Wxp);
  pack_wreg_kernel<<<384, 256, 0, stream>>>(lstm_W, Wreg);
  pack_wl_kernel<<<128, 256, 0, stream>>>(lstm_W, WLg);
  // xw[token][g*256+q] = emb . Wx + lstm_b
  gemm_f32<<<dim3(16, 64), 256, 0, stream>>>(emb, Wxp, lstm_b, xw, 4096, 1024, 256, 0);
  lstm_kernel<<<16, 512, LSTM_LDS, stream>>>(Wreg, WLg, lstm_th, xw, hb);
  pe_add_kernel<<<4096, 256, 0, stream>>>(hb);

  for (int l = 0; l < 2; ++l) {
    qproj_kernel<<<4096, 256, 0, stream>>>(hb, qkv_th + (l * 3 + 0) * 256, qq);
    qproj_kernel<<<4096, 256, 0, stream>>>(hb, qkv_th + (l * 3 + 1) * 256, kk);
    qproj_kernel<<<4096, 256, 0, stream>>>(hb, qkv_th + (l * 3 + 2) * 256, vv);
    attn_kernel<<<dim3(8, 16), 256, ATT_LDS, stream>>>(qq, kk, vv, emb);
    gemm_f32<<<dim3(4, 64), 256, 0, stream>>>(emb, comb_W + l * 65536, comb_b + l * 256,
                                              tmp, 4096, 256, 256, 0);
    ln_kernel<<<4096, 256, 0, stream>>>(hb, tmp, ln1_g + l * 256, ln1_b + l * 256);
    qproj_kernel<<<4096, 256, 0, stream>>>(hb, ffn_th + l * 256, vv);
    gemm_f32<<<dim3(16, 64), 256, 0, stream>>>(vv, lin1_W + l * 262144, lin1_b + l * 1024,
                                               xw, 4096, 1024, 256, 1);
    gemm_f32<<<dim3(4, 64), 256, 0, stream>>>(xw, lin2_W + l * 262144, lin2_b + l * 256,
                                              tmp, 4096, 256, 1024, 0);
    ln_kernel<<<4096, 256, 0, stream>>>(hb, tmp, ln2_g + l * 256, ln2_b + l * 256);
  }

  pool_cls_kernel<<<16, 256, 0, stream>>>(hb, cls_W, cls_b, (float*)d_out);
}

// Round 4
// 1440.380 us; speedup vs baseline: 2.9145x; 1.1984x over previous
//
#include <hip/hip_runtime.h>
#include <hip/hip_bf16.h>

// Problem constants: B=16, S=256, V=32000, E=256, H=8, L=2, FFN=1024, NC=4, DK=32, NQ=256

typedef __attribute__((ext_vector_type(8))) short bf8v;   // 8 bf16 in 4 VGPRs
typedef __attribute__((ext_vector_type(4))) float f4v;    // MFMA accumulator
#define MFMA16 __builtin_amdgcn_mfma_f32_16x16x32_bf16

__device__ __forceinline__ unsigned short f2bf(float f) {
  unsigned u = __builtin_bit_cast(unsigned, f);
  u += 0x7fffu + ((u >> 16) & 1u);
  return (unsigned short)(u >> 16);
}
__device__ __forceinline__ float bf2f(unsigned short h) {
  return __builtin_bit_cast(float, ((unsigned)h) << 16);
}
__device__ __forceinline__ float rcp_f(float x) { return __builtin_amdgcn_rcpf(x); }
__device__ __forceinline__ float sigm(float x) { return rcp_f(1.f + __expf(-x)); }
__device__ __forceinline__ float tanh_f(float x) { return 1.f - 2.f * rcp_f(__expf(2.f * x) + 1.f); }

// v_dot2_f32_bf16: acc += a.x*b.x + a.y*b.y  (packed bf16 pairs in uint)
#define DOT2BF(acc, a, b) \
  asm("v_dot2_f32_bf16 %0, %1, %2, %0" : "+v"(acc) : "v"(a), "v"(b))

// ---------------- embedding gather -> bf16 hi/lo ----------------
__global__ void embed_kernel(const int* __restrict__ x, const float* __restrict__ tab,
                             unsigned short* __restrict__ eh, unsigned short* __restrict__ el) {
  int tok = blockIdx.x, tid = threadIdx.x;
  float v = tab[x[tok] * 256 + tid];
  unsigned short h = f2bf(v);
  eh[tok * 256 + tid] = h;
  el[tok * 256 + tid] = f2bf(v - bf2f(h));
}

// ---- transpose + hi/lo split: W [K][N] f32 -> T[n][k] bf16 (hi, lo) ----
__global__ void pack_bt(const float* __restrict__ W, int K, int N,
                        unsigned short* __restrict__ Th, unsigned short* __restrict__ Tl) {
  __shared__ float tile[64][65];
  int n0 = blockIdx.x * 64, k0 = blockIdx.y * 64;
  int tid = threadIdx.x, tx = tid & 63, ty = tid >> 6;
  for (int r = ty; r < 64; r += 4) tile[r][tx] = W[(k0 + r) * N + n0 + tx];
  __syncthreads();
  for (int r = ty; r < 64; r += 4) {
    float v = tile[tx][r];  // = W[k0+tx][n0+r]
    unsigned short h = f2bf(v);
    int o = (n0 + r) * K + k0 + tx;
    Th[o] = h;
    Tl[o] = f2bf(v - bf2f(h));
  }
}

// ---- pack h-part of gates 0..2 as bf16 d-pairs, uint4-friendly layout ----
__global__ void pack_wreg_kernel(const float* __restrict__ lstmW, unsigned* __restrict__ Wreg) {
  int o = blockIdx.x * 256 + threadIdx.x;  // < 98304
  int c = o & 3;
  int q = (o >> 2) & 255;
  int i4 = (o >> 10) & 15;
  int gs = o >> 14;  // 0..5
  int gi = gs >> 1, s = gs & 1;
  int i = i4 * 4 + c;
  int d = s * 128 + 2 * i;
  unsigned lo = f2bf(lstmW[(gi * 512 + 256 + d) * 256 + q]);
  unsigned hi = f2bf(lstmW[(gi * 512 + 256 + d + 1) * 256 + q]);
  Wreg[o] = lo | (hi << 16);
}

// ---- pack h-part of gate 3 as bf16 d-pairs for LDS, uint4-friendly ----
__global__ void pack_wl_kernel(const float* __restrict__ lstmW, unsigned* __restrict__ WLg) {
  int o = blockIdx.x * 256 + threadIdx.x;  // < 32768
  int c = o & 3;
  int q = (o >> 2) & 255;
  int p4 = o >> 10;  // 0..31
  int d = 2 * (p4 * 4 + c);
  unsigned lo = f2bf(lstmW[(3 * 512 + 256 + d) * 256 + q]);
  unsigned hi = f2bf(lstmW[(3 * 512 + 256 + d + 1) * 256 + q]);
  WLg[o] = lo | (hi << 16);
}

// ---------------- MFMA GEMM, 3-pass hi/lo split: C = A*B + bias ----------------
// A: [M][K] bf16 hi/lo. B: [N][K] bf16 hi/lo (pre-transposed). 128x128 tile, BK=32.
// mode 0: write f32 Cf. mode 1: relu, write bf16 hi/lo (Ch, Cl).
__global__ void __launch_bounds__(256) gemm_mfma(const unsigned short* __restrict__ Ah,
                                                 const unsigned short* __restrict__ Al,
                                                 const unsigned short* __restrict__ Bh,
                                                 const unsigned short* __restrict__ Bl,
                                                 const float* __restrict__ bias,
                                                 float* __restrict__ Cf,
                                                 unsigned short* __restrict__ Ch,
                                                 unsigned short* __restrict__ Cl,
                                                 int M, int N, int K, int mode) {
  __shared__ unsigned short As_h[128 * 40];
  __shared__ unsigned short As_l[128 * 40];
  __shared__ unsigned short Bs_h[128 * 40];
  __shared__ unsigned short Bs_l[128 * 40];

  const int tid = threadIdx.x;
  const int lane = tid & 63;
  const int wid = tid >> 6;
  const int wr = wid >> 1, wc = wid & 1;  // wave tile 64x64 within 128x128
  const int bm = blockIdx.y * 128, bn = blockIdx.x * 128;

  const int srow = tid >> 2;        // 64 rows per pass
  const int scol = (tid & 3) * 8;   // 8 bf16 = 16B

  f4v acc[4][4] = {};

  for (int kt = 0; kt < K; kt += 32) {
#pragma unroll
    for (int p = 0; p < 2; ++p) {
      int r = srow + p * 64;
      *(uint4*)(&As_h[r * 40 + scol]) = *(const uint4*)(&Ah[(bm + r) * K + kt + scol]);
      *(uint4*)(&As_l[r * 40 + scol]) = *(const uint4*)(&Al[(bm + r) * K + kt + scol]);
      *(uint4*)(&Bs_h[r * 40 + scol]) = *(const uint4*)(&Bh[(bn + r) * K + kt + scol]);
      *(uint4*)(&Bs_l[r * 40 + scol]) = *(const uint4*)(&Bl[(bn + r) * K + kt + scol]);
    }
    __syncthreads();

    bf8v a_h[4], a_l[4], b_h[4], b_l[4];
    const int kq = (lane >> 4) * 8;
#pragma unroll
    for (int f = 0; f < 4; ++f) {
      int ar = (wr * 64 + f * 16 + (lane & 15)) * 40 + kq;
      int br = (wc * 64 + f * 16 + (lane & 15)) * 40 + kq;
      a_h[f] = *(const bf8v*)(&As_h[ar]);
      a_l[f] = *(const bf8v*)(&As_l[ar]);
      b_h[f] = *(const bf8v*)(&Bs_h[br]);
      b_l[f] = *(const bf8v*)(&Bs_l[br]);
    }
#pragma unroll
    for (int fm = 0; fm < 4; ++fm)
#pragma unroll
      for (int fn = 0; fn < 4; ++fn) {
        acc[fm][fn] = MFMA16(a_h[fm], b_h[fn], acc[fm][fn], 0, 0, 0);
        acc[fm][fn] = MFMA16(a_h[fm], b_l[fn], acc[fm][fn], 0, 0, 0);
        acc[fm][fn] = MFMA16(a_l[fm], b_h[fn], acc[fm][fn], 0, 0, 0);
      }
    __syncthreads();
  }

#pragma unroll
  for (int fm = 0; fm < 4; ++fm)
#pragma unroll
    for (int fn = 0; fn < 4; ++fn) {
      int c = bn + wc * 64 + fn * 16 + (lane & 15);
      int r0 = bm + wr * 64 + fm * 16 + ((lane >> 4) << 2);
      float bv = bias[c];
#pragma unroll
      for (int j = 0; j < 4; ++j) {
        float v = acc[fm][fn][j] + bv;
        if (mode == 1) {
          v = fmaxf(v, 0.f);
          unsigned short h = f2bf(v);
          Ch[(r0 + j) * N + c] = h;
          Cl[(r0 + j) * N + c] = f2bf(v - bf2f(h));
        } else {
          Cf[(r0 + j) * N + c] = v;
        }
      }
    }
}

// ---------------- QLSTM: one block per batch, all comm intra-block ----------------
__global__ void __launch_bounds__(512)
__attribute__((amdgpu_waves_per_eu(2, 2)))
lstm_kernel(const unsigned* __restrict__ Wreg,
            const unsigned* __restrict__ WLg,
            const float* __restrict__ lstmTh,
            const float* __restrict__ xw,
            float* __restrict__ hb) {
  extern __shared__ char smem[];
  unsigned* WL = (unsigned*)smem;               // [32][256] uint4 rows (131072 B)
  float* part = (float*)(smem + 131072);        // [8][256]  (g*2+s, q)
  float* qv = part + 2048;                      // [1024]
  float* wtot = qv + 1024;                      // [16]  (wave, slot)
  unsigned* hp = (unsigned*)(wtot + 16);        // [128] packed bf16 h pairs (16B aligned)

  const int t = threadIdx.x;
  const int b = blockIdx.x;
  const int q = t & 255;
  const int s = t >> 8;          // d-half: d in [s*128, s*128+128)
  const int lane = t & 63;
  const int w = t >> 6;          // wave 0..7

  {
    const uint4* src = (const uint4*)WLg;
    uint4* dst = (uint4*)WL;
    for (int j = t; j < 8192; j += 512) dst[j] = src[j];
  }
  const uint4* Wreg4 = (const uint4*)Wreg;
  uint4 wreg[48];
#pragma unroll
  for (int j = 0; j < 48; ++j) {
    int gi = j >> 4, i4 = j & 15;
    wreg[j] = Wreg4[((gi * 2 + s) * 16 + i4) * 256 + q];
  }
  const float thA = lstmTh[t];          // gate s, col q
  const float thB = lstmTh[512 + t];    // gate s+2, col q
  float cx = 0.f;                       // valid for t<256 (q-owner)
  if (t < 128) hp[t] = 0u;              // h0 = 0
  __syncthreads();

  const int xbase = (b << 8) * 1024;
  const uint4* WL4 = (const uint4*)WL;
  const uint4* hp4 = (const uint4*)hp;

  for (int st = 0; st < 256; ++st) {
    float xa = xw[xbase + st * 1024 + t];
    float xb = xw[xbase + st * 1024 + 512 + t];

    float a0 = 0.f, a1 = 0.f, a2 = 0.f, a3 = 0.f;
#pragma unroll
    for (int i4 = 0; i4 < 16; ++i4) {
      uint4 hh = hp4[(s << 4) + i4];                 // broadcast b128
      uint4 w3 = WL4[((s << 4) + i4) * 256 + q];     // sequential b128
      uint4 w0 = wreg[i4];
      uint4 w1 = wreg[16 + i4];
      uint4 w2 = wreg[32 + i4];
      DOT2BF(a0, w0.x, hh.x); DOT2BF(a0, w0.y, hh.y);
      DOT2BF(a0, w0.z, hh.z); DOT2BF(a0, w0.w, hh.w);
      DOT2BF(a1, w1.x, hh.x); DOT2BF(a1, w1.y, hh.y);
      DOT2BF(a1, w1.z, hh.z); DOT2BF(a1, w1.w, hh.w);
      DOT2BF(a2, w2.x, hh.x); DOT2BF(a2, w2.y, hh.y);
      DOT2BF(a2, w2.z, hh.z); DOT2BF(a2, w2.w, hh.w);
      DOT2BF(a3, w3.x, hh.x); DOT2BF(a3, w3.y, hh.y);
      DOT2BF(a3, w3.z, hh.z); DOT2BF(a3, w3.w, hh.w);
    }
    part[(0 * 2 + s) * 256 + q] = a0;
    part[(1 * 2 + s) * 256 + q] = a1;
    part[(2 * 2 + s) * 256 + q] = a2;
    part[(3 * 2 + s) * 256 + q] = a3;
    __syncthreads();

    int gA = s, gB = s + 2;
    float zA = part[(gA * 2 + 0) * 256 + q] + part[(gA * 2 + 1) * 256 + q] + xa + thA;
    float zB = part[(gB * 2 + 0) * 256 + q] + part[(gB * 2 + 1) * 256 + q] + xb + thB;
    float vA = __cosf(zA);
    float vB = __cosf(zB);

#pragma unroll
    for (int off = 1; off < 64; off <<= 1) {
      float oA = __shfl_up(vA, off, 64);
      float oB = __shfl_up(vB, off, 64);
      if (lane >= off) { vA *= oA; vB *= oB; }
    }
    if (lane == 63) { wtot[w * 2] = vA; wtot[w * 2 + 1] = vB; }
    __syncthreads();
    {
      float pA = 1.f, pB = 1.f;
      int w0 = w & ~3;
      for (int k = w0; k < w; ++k) { pA *= wtot[k * 2]; pB *= wtot[k * 2 + 1]; }
      vA *= pA;
      vB *= pB;
    }
    qv[t] = vA;
    qv[512 + t] = vB;
    __syncthreads();

    if (t < 256) {
      float fg = sigm(qv[t]);
      float ig = sigm(qv[256 + t]);
      float gg = tanh_f(qv[512 + t]);
      float og = sigm(qv[768 + t]);
      cx = fg * cx + ig * gg;
      float hv = og * tanh_f(cx);
      hb[((b << 8) + st) * 256 + t] = hv;
      float nb = __shfl_xor(hv, 1, 64);
      if ((t & 1) == 0) hp[t >> 1] = (unsigned)f2bf(hv) | ((unsigned)f2bf(nb) << 16);
    }
    __syncthreads();
  }
}

// ---------------- h += sinusoidal PE ----------------
__global__ void pe_add_kernel(float* __restrict__ h) {
  int tok = blockIdx.x, tid = threadIdx.x;
  int s = tok & 255;
  int j = tid >> 1;
  float div = __expf((float)j * -0.07195578415622253f);
  float ang = (float)s * div;
  float pe = (tid & 1) ? __cosf(ang) : __sinf(ang);
  h[tok * 256 + tid] += pe;
}

// ---------------- qproj: out = cumprod(cos(h + theta)); f32 or bf16 hi/lo ----------------
__global__ void qproj_kernel(const float* __restrict__ hin, const float* __restrict__ theta,
                             float* __restrict__ outf, unsigned short* __restrict__ outh,
                             unsigned short* __restrict__ outl) {
  __shared__ float wtot[4];
  int tok = blockIdx.x, tid = threadIdx.x, lane = tid & 63, wid = tid >> 6;
  float v = __cosf(hin[tok * 256 + tid] + theta[tid]);
#pragma unroll
  for (int off = 1; off < 64; off <<= 1) {
    float o = __shfl_up(v, off, 64);
    if (lane >= off) v *= o;
  }
  if (lane == 63) wtot[wid] = v;
  __syncthreads();
  float pre = 1.f;
  for (int w = 0; w < wid; ++w) pre *= wtot[w];
  v *= pre;
  int o = tok * 256 + tid;
  if (outh) {
    unsigned short h = f2bf(v);
    outh[o] = h;
    outl[o] = f2bf(v - bf2f(h));
  } else {
    outf[o] = v;
  }
}

// ---------------- attention: one block per (head, batch); wave-per-row ----------------
__global__ void __launch_bounds__(256, 1) attn_kernel(const float* __restrict__ qb,
                                                      const float* __restrict__ kb,
                                                      const float* __restrict__ vb,
                                                      unsigned short* __restrict__ outh,
                                                      unsigned short* __restrict__ outl) {
  extern __shared__ float sm[];
  float* Qs = sm;                 // [256][33]
  float* Ks = Qs + 256 * 33;
  float* Vs = Ks + 256 * 33;
  float* ps = Vs + 256 * 33;      // [4][256]
  int hd = blockIdx.x, b = blockIdx.y;
  int tid = threadIdx.x, lane = tid & 63, wid = tid >> 6;
  const float scale = 0.17677669529663687f;  // 1/sqrt(32)

  for (int i = tid; i < 256 * 32; i += 256) {
    int r = i >> 5, d = i & 31;
    int src = (b * 256 + r) * 256 + hd * 32 + d;
    Qs[r * 33 + d] = qb[src];
    Ks[r * 33 + d] = kb[src];
    Vs[r * 33 + d] = vb[src];
  }
  __syncthreads();

  float* pw = ps + wid * 256;
  for (int r = wid; r < 256; r += 4) {
    float qreg[32];
#pragma unroll
    for (int d = 0; d < 32; ++d) qreg[d] = Qs[r * 33 + d];
    float s[4];
#pragma unroll
    for (int j = 0; j < 4; ++j) {
      int k = lane + 64 * j;
      float a = 0.f;
#pragma unroll
      for (int d = 0; d < 32; ++d) a += qreg[d] * Ks[k * 33 + d];
      s[j] = a * scale;
    }
    float m = fmaxf(fmaxf(s[0], s[1]), fmaxf(s[2], s[3]));
#pragma unroll
    for (int off = 32; off; off >>= 1) m = fmaxf(m, __shfl_xor(m, off, 64));
    float p[4], sum = 0.f;
#pragma unroll
    for (int j = 0; j < 4; ++j) { p[j] = __expf(s[j] - m); sum += p[j]; }
#pragma unroll
    for (int off = 32; off; off >>= 1) sum += __shfl_xor(sum, off, 64);
    float inv = rcp_f(sum);
#pragma unroll
    for (int j = 0; j < 4; ++j) pw[lane + 64 * j] = p[j] * inv;
    int d = lane & 31, half = lane >> 5;
    float a = 0.f;
#pragma unroll 8
    for (int i2 = 0; i2 < 128; ++i2) {
      int k = half * 128 + i2;
      a += pw[k] * Vs[k * 33 + d];
    }
    a += __shfl_down(a, 32, 64);
    if (lane < 32) {
      int o = (b * 256 + r) * 256 + hd * 32 + d;
      unsigned short h = f2bf(a);
      outh[o] = h;
      outl[o] = f2bf(a - bf2f(h));
    }
  }
}

// ---------------- layernorm(h + delta) -> h ----------------
__global__ void ln_kernel(float* __restrict__ hio, const float* __restrict__ delta,
                          const float* __restrict__ gamma, const float* __restrict__ beta) {
  __shared__ float red[16];
  int tok = blockIdx.x, tid = threadIdx.x, lane = tid & 63, wid = tid >> 6;
  float v = hio[tok * 256 + tid] + delta[tok * 256 + tid];
  float s1 = v, s2 = v * v;
#pragma unroll
  for (int off = 32; off; off >>= 1) {
    s1 += __shfl_xor(s1, off, 64);
    s2 += __shfl_xor(s2, off, 64);
  }
  if (lane == 0) { red[wid] = s1; red[wid + 8] = s2; }
  __syncthreads();
  float t1 = red[0] + red[1] + red[2] + red[3];
  float t2 = red[8] + red[9] + red[10] + red[11];
  float mean = t1 * (1.f / 256.f);
  float var = t2 * (1.f / 256.f) - mean * mean;
  float w = rsqrtf(var + 1e-5f);
  hio[tok * 256 + tid] = (v - mean) * w * gamma[tid] + beta[tid];
}

// ---------------- mean pool over S + classifier ----------------
__global__ void pool_cls_kernel(const float* __restrict__ h, const float* __restrict__ clsW,
                                const float* __restrict__ clsb, float* __restrict__ out) {
  __shared__ float pl[256];
  __shared__ float red[8];
  int b = blockIdx.x, tid = threadIdx.x, lane = tid & 63, wid = tid >> 6;
  float s = 0.f;
  for (int t = 0; t < 256; ++t) s += h[(b * 256 + t) * 256 + tid];
  pl[tid] = s * (1.f / 256.f);
  __syncthreads();
  for (int c = 0; c < 4; ++c) {
    float v = pl[tid] * clsW[tid * 4 + c];
#pragma unroll
    for (int off = 32; off; off >>= 1) v += __shfl_xor(v, off, 64);
    if (lane == 0) red[wid] = v;
    __syncthreads();
    if (tid == 0) out[b * 4 + c] = red[0] + red[1] + red[2] + red[3] + clsb[c];
    __syncthreads();
  }
}

extern "C" void kernel_launch(void* const* d_in, const int* in_sizes, int n_in,
                              void* d_out, int out_size, void* d_ws, size_t ws_size,
                              hipStream_t stream) {
  const int* x = (const int*)d_in[0];
  const float* token_emb = (const float*)d_in[1];
  const float* lstm_W = (const float*)d_in[2];
  const float* lstm_b = (const float*)d_in[3];
  const float* lstm_th = (const float*)d_in[4];
  const float* ln1_g = (const float*)d_in[5];
  const float* ln1_b = (const float*)d_in[6];
  const float* ln2_g = (const float*)d_in[7];
  const float* ln2_b = (const float*)d_in[8];
  const float* qkv_th = (const float*)d_in[9];
  const float* comb_W = (const float*)d_in[10];
  const float* comb_b = (const float*)d_in[11];
  const float* ffn_th = (const float*)d_in[12];
  const float* lin1_W = (const float*)d_in[13];
  const float* lin1_b = (const float*)d_in[14];
  const float* lin2_W = (const float*)d_in[15];
  const float* lin2_b = (const float*)d_in[16];
  const float* cls_W = (const float*)d_in[17];
  const float* cls_b = (const float*)d_in[18];

  float* ws = (float*)d_ws;
  typedef unsigned short ushort_t;
  // region 0 (1M f32): emb hi/lo before loop; attn hi/lo inside loop
  ushort_t* emb_h = (ushort_t*)ws;
  ushort_t* emb_l = emb_h + 1048576;
  ushort_t* att_h = emb_h;
  ushort_t* att_l = emb_l;
  // region 1 (4M f32): xw f32 (pre-loop) / ffh hi/lo (in-loop)
  float* xw = ws + 1048576;
  ushort_t* ffh_h = (ushort_t*)xw;
  ushort_t* ffh_l = ffh_h + 4194304;
  float* hb = ws + 5242880;   // 1M
  float* qq = ws + 6291456;   // 1M
  float* kk = ws + 7340032;   // 1M
  float* vv = ws + 8388608;   // 1M
  float* tmp = ws + 9437184;  // 1M; first 131072 u32 reused pre-loop for lstm packs
  unsigned* Wreg = (unsigned*)tmp;            // 98304 uints
  unsigned* WLg = (unsigned*)(tmp + 98304);   // 32768 uints
  ushort_t* ffq_h = (ushort_t*)(ws + 10485760);  // 1M ushort
  ushort_t* ffq_l = ffq_h + 1048576;
  // weight packs (from 11M f32)
  ushort_t* wxt_h = (ushort_t*)(ws + 11534336);     // 262144
  ushort_t* wxt_l = wxt_h + 262144;
  ushort_t* cmb_h = wxt_l + 262144;                 // 2*65536
  ushort_t* cmb_l = cmb_h + 131072;
  ushort_t* l1_h = cmb_l + 131072;                  // 2*262144
  ushort_t* l1_l = l1_h + 524288;
  ushort_t* l2_h = l1_l + 524288;                   // 2*262144
  ushort_t* l2_l = l2_h + 524288;

  const int LSTM_LDS = 131072 + 8192 + 4096 + 64 + 512;  // 143936 B
  const int ATT_LDS = (3 * 256 * 33 + 4 * 256) * 4;      // 105472 B
  (void)hipFuncSetAttribute(reinterpret_cast<const void*>(lstm_kernel),
                            hipFuncAttributeMaxDynamicSharedMemorySize, LSTM_LDS);
  (void)hipFuncSetAttribute(reinterpret_cast<const void*>(attn_kernel),
                            hipFuncAttributeMaxDynamicSharedMemorySize, ATT_LDS);

  embed_kernel<<<4096, 256, 0, stream>>>(x, token_emb, emb_h, emb_l);
  pack_wreg_kernel<<<384, 256, 0, stream>>>(lstm_W, Wreg);
  pack_wl_kernel<<<128, 256, 0, stream>>>(lstm_W, WLg);
  // Wx^T per gate: rows n = g*256+q, cols k
  for (int g = 0; g < 4; ++g)
    pack_bt<<<dim3(4, 4), 256, 0, stream>>>(lstm_W + g * 131072, 256, 256,
                                            wxt_h + g * 65536, wxt_l + g * 65536);
  for (int l = 0; l < 2; ++l) {
    pack_bt<<<dim3(4, 4), 256, 0, stream>>>(comb_W + l * 65536, 256, 256,
                                            cmb_h + l * 65536, cmb_l + l * 65536);
    pack_bt<<<dim3(16, 4), 256, 0, stream>>>(lin1_W + l * 262144, 256, 1024,
                                             l1_h + l * 262144, l1_l + l * 262144);
    pack_bt<<<dim3(4, 16), 256, 0, stream>>>(lin2_W + l * 262144, 1024, 256,
                                             l2_h + l * 262144, l2_l + l * 262144);
  }

  // xw = emb @ Wx + lstm_b : M=4096 N=1024 K=256
  gemm_mfma<<<dim3(8, 32), 256, 0, stream>>>(emb_h, emb_l, wxt_h, wxt_l, lstm_b,
                                             xw, nullptr, nullptr, 4096, 1024, 256, 0);
  lstm_kernel<<<16, 512, LSTM_LDS, stream>>>(Wreg, WLg, lstm_th, xw, hb);
  pe_add_kernel<<<4096, 256, 0, stream>>>(hb);

  for (int l = 0; l < 2; ++l) {
    qproj_kernel<<<4096, 256, 0, stream>>>(hb, qkv_th + (l * 3 + 0) * 256, qq, nullptr, nullptr);
    qproj_kernel<<<4096, 256, 0, stream>>>(hb, qkv_th + (l * 3 + 1) * 256, kk, nullptr, nullptr);
    qproj_kernel<<<4096, 256, 0, stream>>>(hb, qkv_th + (l * 3 + 2) * 256, vv, nullptr, nullptr);
    attn_kernel<<<dim3(8, 16), 256, ATT_LDS, stream>>>(qq, kk, vv, att_h, att_l);
    gemm_mfma<<<dim3(2, 32), 256, 0, stream>>>(att_h, att_l, cmb_h + l * 65536,
                                               cmb_l + l * 65536, comb_b + l * 256,
                                               tmp, nullptr, nullptr, 4096, 256, 256, 0);
    ln_kernel<<<4096, 256, 0, stream>>>(hb, tmp, ln1_g + l * 256, ln1_b + l * 256);
    qproj_kernel<<<4096, 256, 0, stream>>>(hb, ffn_th + l * 256, nullptr, ffq_h, ffq_l);
    gemm_mfma<<<dim3(8, 32), 256, 0, stream>>>(ffq_h, ffq_l, l1_h + l * 262144,
                                               l1_l + l * 262144, lin1_b + l * 1024,
                                               nullptr, ffh_h, ffh_l, 4096, 1024, 256, 1);
    gemm_mfma<<<dim3(2, 32), 256, 0, stream>>>(ffh_h, ffh_l, l2_h + l * 262144,
                                               l2_l + l * 262144, lin2_b + l * 256,
                                               tmp, nullptr, nullptr, 4096, 256, 1024, 0);
    ln_kernel<<<4096, 256, 0, stream>>>(hb, tmp, ln2_g + l * 256, ln2_b + l * 256);
  }

  pool_cls_kernel<<<16, 256, 0, stream>>>(hb, cls_W, cls_b, (float*)d_out);
}

// Round 5
// 1427.245 us; speedup vs baseline: 2.9413x; 1.0092x over previous
//
#include <hip/hip_runtime.h>
#include <hip/hip_bf16.h>

// Problem constants: B=16, S=256, V=32000, E=256, H=8, L=2, FFN=1024, NC=4, DK=32, NQ=256

typedef __attribute__((ext_vector_type(8))) short bf8v;   // 8 bf16 in 4 VGPRs
typedef __attribute__((ext_vector_type(4))) float f4v;    // MFMA accumulator
#define MFMA16 __builtin_amdgcn_mfma_f32_16x16x32_bf16

__device__ __forceinline__ unsigned short f2bf(float f) {
  unsigned u = __builtin_bit_cast(unsigned, f);
  u += 0x7fffu + ((u >> 16) & 1u);
  return (unsigned short)(u >> 16);
}
__device__ __forceinline__ float rcp_f(float x) { return __builtin_amdgcn_rcpf(x); }
__device__ __forceinline__ float sigm(float x) { return rcp_f(1.f + __expf(-x)); }
__device__ __forceinline__ float tanh_f(float x) { return 1.f - 2.f * rcp_f(__expf(2.f * x) + 1.f); }

// v_dot2_f32_bf16: acc += a.x*b.x + a.y*b.y  (packed bf16 pairs in uint)
#define DOT2BF(acc, a, b) \
  asm("v_dot2_f32_bf16 %0, %1, %2, %0" : "+v"(acc) : "v"(a), "v"(b))

// ---------------- embedding gather -> bf16 ----------------
__global__ void embed_kernel(const int* __restrict__ x, const float* __restrict__ tab,
                             unsigned short* __restrict__ eb) {
  int tok = blockIdx.x, tid = threadIdx.x;
  eb[tok * 256 + tid] = f2bf(tab[x[tok] * 256 + tid]);
}

// ---- transpose to bf16: W [K][N] f32 -> T[n][k] bf16 ; blockIdx.z batches slices ----
__global__ void pack_bt(const float* __restrict__ W, int K, int N,
                        unsigned short* __restrict__ Th, long wz, long tz) {
  __shared__ float tile[64][65];
  W += (long)blockIdx.z * wz;
  Th += (long)blockIdx.z * tz;
  int n0 = blockIdx.x * 64, k0 = blockIdx.y * 64;
  int tid = threadIdx.x, tx = tid & 63, ty = tid >> 6;
  for (int r = ty; r < 64; r += 4) tile[r][tx] = W[(k0 + r) * N + n0 + tx];
  __syncthreads();
  for (int r = ty; r < 64; r += 4) {
    Th[(n0 + r) * K + k0 + tx] = f2bf(tile[tx][r]);  // = W[k0+tx][n0+r]
  }
}

// ---- pack h-part of gates 0..2 as bf16 d-pairs; quarter-split (s=0..3, 64 d each) ----
// uint o = (((gi*4+s)*8 + i4)*256 + q)*4 + c ; pair i = i4*4+c, d = s*64 + 2i
__global__ void pack_wreg_kernel(const float* __restrict__ lstmW, unsigned* __restrict__ Wreg) {
  int o = blockIdx.x * 256 + threadIdx.x;  // < 98304
  int c = o & 3;
  int q = (o >> 2) & 255;
  int i4 = (o >> 10) & 7;
  int s = (o >> 13) & 3;
  int gi = o >> 15;  // 0..2
  int d = s * 64 + 2 * (i4 * 4 + c);
  unsigned lo = f2bf(lstmW[(gi * 512 + 256 + d) * 256 + q]);
  unsigned hi = f2bf(lstmW[(gi * 512 + 256 + d + 1) * 256 + q]);
  Wreg[o] = lo | (hi << 16);
}

// ---- pack h-part of gate 3 as bf16 d-pairs for LDS ----
// uint o = (p4*256 + q)*4 + c ; pair p = p4*4+c, d = 2p
__global__ void pack_wl_kernel(const float* __restrict__ lstmW, unsigned* __restrict__ WLg) {
  int o = blockIdx.x * 256 + threadIdx.x;  // < 32768
  int c = o & 3;
  int q = (o >> 2) & 255;
  int p4 = o >> 10;  // 0..31
  int d = 2 * (p4 * 4 + c);
  unsigned lo = f2bf(lstmW[(3 * 512 + 256 + d) * 256 + q]);
  unsigned hi = f2bf(lstmW[(3 * 512 + 256 + d + 1) * 256 + q]);
  WLg[o] = lo | (hi << 16);
}

// ---------------- MFMA GEMM, single-pass bf16: C = A*B + bias ----------------
// A: [M][K] bf16. B: [N][K] bf16 (pre-transposed). 128x128 tile, BK=32.
// mode 0: write f32 Cf. mode 1: relu, write bf16 Cb.
__global__ void __launch_bounds__(256) gemm_mfma(const unsigned short* __restrict__ A,
                                                 const unsigned short* __restrict__ B,
                                                 const float* __restrict__ bias,
                                                 float* __restrict__ Cf,
                                                 unsigned short* __restrict__ Cb,
                                                 int M, int N, int K, int mode) {
  __shared__ unsigned short As[128 * 40];
  __shared__ unsigned short Bs[128 * 40];

  const int tid = threadIdx.x;
  const int lane = tid & 63;
  const int wid = tid >> 6;
  const int wr = wid >> 1, wc = wid & 1;  // wave tile 64x64 within 128x128
  const int bm = blockIdx.y * 128, bn = blockIdx.x * 128;

  const int srow = tid >> 2;        // 64 rows per pass
  const int scol = (tid & 3) * 8;   // 8 bf16 = 16B

  f4v acc[4][4] = {};

  for (int kt = 0; kt < K; kt += 32) {
#pragma unroll
    for (int p = 0; p < 2; ++p) {
      int r = srow + p * 64;
      *(uint4*)(&As[r * 40 + scol]) = *(const uint4*)(&A[(bm + r) * K + kt + scol]);
      *(uint4*)(&Bs[r * 40 + scol]) = *(const uint4*)(&B[(bn + r) * K + kt + scol]);
    }
    __syncthreads();

    bf8v a[4], b[4];
    const int kq = (lane >> 4) * 8;
#pragma unroll
    for (int f = 0; f < 4; ++f) {
      a[f] = *(const bf8v*)(&As[(wr * 64 + f * 16 + (lane & 15)) * 40 + kq]);
      b[f] = *(const bf8v*)(&Bs[(wc * 64 + f * 16 + (lane & 15)) * 40 + kq]);
    }
#pragma unroll
    for (int fm = 0; fm < 4; ++fm)
#pragma unroll
      for (int fn = 0; fn < 4; ++fn)
        acc[fm][fn] = MFMA16(a[fm], b[fn], acc[fm][fn], 0, 0, 0);
    __syncthreads();
  }

#pragma unroll
  for (int fm = 0; fm < 4; ++fm)
#pragma unroll
    for (int fn = 0; fn < 4; ++fn) {
      int c = bn + wc * 64 + fn * 16 + (lane & 15);
      int r0 = bm + wr * 64 + fm * 16 + ((lane >> 4) << 2);
      float bv = bias[c];
#pragma unroll
      for (int j = 0; j < 4; ++j) {
        float v = acc[fm][fn][j] + bv;
        if (mode == 1) {
          Cb[(r0 + j) * N + c] = f2bf(fmaxf(v, 0.f));
        } else {
          Cf[(r0 + j) * N + c] = v;
        }
      }
    }
}

// ---------------- QLSTM: one block per batch; 1024 threads; quarter d-split ----------------
// Thread t: q = t&255, s = t>>8 (d-quarter of 64). 3 gates in 24 uint4 regs (96 VGPR),
// gate 3 in LDS (128 KiB). Thread t finalizes gate s, col q.
__global__ void __launch_bounds__(1024, 4) lstm_kernel(const unsigned* __restrict__ Wreg,
                                                       const unsigned* __restrict__ WLg,
                                                       const float* __restrict__ lstmTh,
                                                       const float* __restrict__ xw,
                                                       float* __restrict__ hb) {
  extern __shared__ char smem[];
  unsigned* WL = (unsigned*)smem;               // [32][256] uint4 rows (131072 B)
  float* part = (float*)(smem + 131072);        // [16][256]  (g*4+s, q)
  float* qv = part + 4096;                      // [1024]
  float* wtot = qv + 1024;                      // [16]
  unsigned* hp = (unsigned*)(wtot + 16);        // [128] packed bf16 h pairs (16B aligned)

  const int t = threadIdx.x;
  const int b = blockIdx.x;
  const int q = t & 255;
  const int s = t >> 8;          // quarter: d in [s*64, s*64+64)
  const int lane = t & 63;
  const int w = t >> 6;          // wave 0..15 (gate s = waves 4s..4s+3)

  {
    const uint4* src = (const uint4*)WLg;
    uint4* dst = (uint4*)WL;
    for (int j = t; j < 8192; j += 1024) dst[j] = src[j];
  }
  const uint4* Wreg4 = (const uint4*)Wreg;
  uint4 wreg[24];
#pragma unroll
  for (int j = 0; j < 24; ++j) {
    int gi = j >> 3, i4 = j & 7;
    wreg[j] = Wreg4[((gi * 4 + s) * 8 + i4) * 256 + q];
  }
  const float th = lstmTh[t];    // gate s, col q
  float cx = 0.f;                // valid for t<256 (q-owner)
  if (t < 128) hp[t] = 0u;       // h0 = 0
  __syncthreads();

  const int xbase = (b << 8) * 1024;
  const uint4* WL4 = (const uint4*)WL;
  const uint4* hp4 = (const uint4*)hp;

  for (int st = 0; st < 256; ++st) {
    float xv = xw[xbase + st * 1024 + t];

    // ---- GEMV quarter-dots: 4 gates x 64 d (32 pairs = 8 uint4) ----
    float a0 = 0.f, a1 = 0.f, a2 = 0.f, a3 = 0.f;
#pragma unroll
    for (int i4 = 0; i4 < 8; ++i4) {
      uint4 hh = hp4[(s << 3) + i4];                 // broadcast b128
      uint4 w3 = WL4[((s << 3) + i4) * 256 + q];     // sequential b128
      uint4 w0 = wreg[i4];
      uint4 w1 = wreg[8 + i4];
      uint4 w2 = wreg[16 + i4];
      DOT2BF(a0, w0.x, hh.x); DOT2BF(a0, w0.y, hh.y);
      DOT2BF(a0, w0.z, hh.z); DOT2BF(a0, w0.w, hh.w);
      DOT2BF(a1, w1.x, hh.x); DOT2BF(a1, w1.y, hh.y);
      DOT2BF(a1, w1.z, hh.z); DOT2BF(a1, w1.w, hh.w);
      DOT2BF(a2, w2.x, hh.x); DOT2BF(a2, w2.y, hh.y);
      DOT2BF(a2, w2.z, hh.z); DOT2BF(a2, w2.w, hh.w);
      DOT2BF(a3, w3.x, hh.x); DOT2BF(a3, w3.y, hh.y);
      DOT2BF(a3, w3.z, hh.z); DOT2BF(a3, w3.w, hh.w);
    }
    part[(0 * 4 + s) * 256 + q] = a0;
    part[(1 * 4 + s) * 256 + q] = a1;
    part[(2 * 4 + s) * 256 + q] = a2;
    part[(3 * 4 + s) * 256 + q] = a3;
    __syncthreads();

    // ---- finalize z for gate s, col q ----
    float z = part[(s * 4 + 0) * 256 + q] + part[(s * 4 + 1) * 256 + q] +
              part[(s * 4 + 2) * 256 + q] + part[(s * 4 + 3) * 256 + q] + xv + th;
    float v = __cosf(z);

    // ---- cumprod scan along q (4 waves per gate) ----
#pragma unroll
    for (int off = 1; off < 64; off <<= 1) {
      float o = __shfl_up(v, off, 64);
      if (lane >= off) v *= o;
    }
    if (lane == 63) wtot[w] = v;
    __syncthreads();
    {
      float p = 1.f;
      int w0g = w & ~3;
      for (int k = w0g; k < w; ++k) p *= wtot[k];
      v *= p;
    }
    qv[t] = v;   // gate-major: qv[g*256+q]
    __syncthreads();

    // ---- combine gates, update cx/h (threads 0..255 own q) ----
    if (t < 256) {
      float fg = sigm(qv[t]);
      float ig = sigm(qv[256 + t]);
      float gg = tanh_f(qv[512 + t]);
      float og = sigm(qv[768 + t]);
      cx = fg * cx + ig * gg;
      float hv = og * tanh_f(cx);
      hb[((b << 8) + st) * 256 + t] = hv;
      float nb = __shfl_xor(hv, 1, 64);
      if ((t & 1) == 0) hp[t >> 1] = (unsigned)f2bf(hv) | ((unsigned)f2bf(nb) << 16);
    }
    __syncthreads();
  }
}

// ---------------- h += sinusoidal PE ----------------
__global__ void pe_add_kernel(float* __restrict__ h) {
  int tok = blockIdx.x, tid = threadIdx.x;
  int s = tok & 255;
  int j = tid >> 1;
  float div = __expf((float)j * -0.07195578415622253f);
  float ang = (float)s * div;
  float pe = (tid & 1) ? __cosf(ang) : __sinf(ang);
  h[tok * 256 + tid] += pe;
}

// ---------------- qproj x3 fused (f32 out, contiguous q/k/v buffers) ----------------
__global__ void qproj3_kernel(const float* __restrict__ hin, const float* __restrict__ thetas,
                              float* __restrict__ outbase) {
  __shared__ float wtot[4];
  int tok = blockIdx.x, y = blockIdx.y;
  int tid = threadIdx.x, lane = tid & 63, wid = tid >> 6;
  const float* theta = thetas + y * 256;
  float* out = outbase + (long)y * 1048576;
  float v = __cosf(hin[tok * 256 + tid] + theta[tid]);
#pragma unroll
  for (int off = 1; off < 64; off <<= 1) {
    float o = __shfl_up(v, off, 64);
    if (lane >= off) v *= o;
  }
  if (lane == 63) wtot[wid] = v;
  __syncthreads();
  float pre = 1.f;
  for (int w = 0; w < wid; ++w) pre *= wtot[w];
  out[tok * 256 + tid] = v * pre;
}

// ---------------- qproj -> bf16 (FFN input) ----------------
__global__ void qproj_bf_kernel(const float* __restrict__ hin, const float* __restrict__ theta,
                                unsigned short* __restrict__ outb) {
  __shared__ float wtot[4];
  int tok = blockIdx.x, tid = threadIdx.x, lane = tid & 63, wid = tid >> 6;
  float v = __cosf(hin[tok * 256 + tid] + theta[tid]);
#pragma unroll
  for (int off = 1; off < 64; off <<= 1) {
    float o = __shfl_up(v, off, 64);
    if (lane >= off) v *= o;
  }
  if (lane == 63) wtot[wid] = v;
  __syncthreads();
  float pre = 1.f;
  for (int w = 0; w < wid; ++w) pre *= wtot[w];
  outb[tok * 256 + tid] = f2bf(v * pre);
}

// ---------------- attention: one block per (head, batch); wave-per-row; bf16 out ----------------
__global__ void __launch_bounds__(256, 1) attn_kernel(const float* __restrict__ qb,
                                                      const float* __restrict__ kb,
                                                      const float* __restrict__ vb,
                                                      unsigned short* __restrict__ outb) {
  extern __shared__ float sm[];
  float* Qs = sm;                 // [256][33]
  float* Ks = Qs + 256 * 33;
  float* Vs = Ks + 256 * 33;
  float* ps = Vs + 256 * 33;      // [4][256]
  int hd = blockIdx.x, b = blockIdx.y;
  int tid = threadIdx.x, lane = tid & 63, wid = tid >> 6;
  const float scale = 0.17677669529663687f;  // 1/sqrt(32)

  for (int i = tid; i < 256 * 32; i += 256) {
    int r = i >> 5, d = i & 31;
    int src = (b * 256 + r) * 256 + hd * 32 + d;
    Qs[r * 33 + d] = qb[src];
    Ks[r * 33 + d] = kb[src];
    Vs[r * 33 + d] = vb[src];
  }
  __syncthreads();

  float* pw = ps + wid * 256;
  for (int r = wid; r < 256; r += 4) {
    float qreg[32];
#pragma unroll
    for (int d = 0; d < 32; ++d) qreg[d] = Qs[r * 33 + d];
    float s[4];
#pragma unroll
    for (int j = 0; j < 4; ++j) {
      int k = lane + 64 * j;
      float a = 0.f;
#pragma unroll
      for (int d = 0; d < 32; ++d) a += qreg[d] * Ks[k * 33 + d];
      s[j] = a * scale;
    }
    float m = fmaxf(fmaxf(s[0], s[1]), fmaxf(s[2], s[3]));
#pragma unroll
    for (int off = 32; off; off >>= 1) m = fmaxf(m, __shfl_xor(m, off, 64));
    float p[4], sum = 0.f;
#pragma unroll
    for (int j = 0; j < 4; ++j) { p[j] = __expf(s[j] - m); sum += p[j]; }
#pragma unroll
    for (int off = 32; off; off >>= 1) sum += __shfl_xor(sum, off, 64);
    float inv = rcp_f(sum);
#pragma unroll
    for (int j = 0; j < 4; ++j) pw[lane + 64 * j] = p[j] * inv;
    int d = lane & 31, half = lane >> 5;
    float a = 0.f;
#pragma unroll 8
    for (int i2 = 0; i2 < 128; ++i2) {
      int k = half * 128 + i2;
      a += pw[k] * Vs[k * 33 + d];
    }
    a += __shfl_down(a, 32, 64);
    if (lane < 32) outb[(b * 256 + r) * 256 + hd * 32 + d] = f2bf(a);
  }
}

// ---------------- layernorm(h + delta) -> h ----------------
__global__ void ln_kernel(float* __restrict__ hio, const float* __restrict__ delta,
                          const float* __restrict__ gamma, const float* __restrict__ beta) {
  __shared__ float red[16];
  int tok = blockIdx.x, tid = threadIdx.x, lane = tid & 63, wid = tid >> 6;
  float v = hio[tok * 256 + tid] + delta[tok * 256 + tid];
  float s1 = v, s2 = v * v;
#pragma unroll
  for (int off = 32; off; off >>= 1) {
    s1 += __shfl_xor(s1, off, 64);
    s2 += __shfl_xor(s2, off, 64);
  }
  if (lane == 0) { red[wid] = s1; red[wid + 8] = s2; }
  __syncthreads();
  float t1 = red[0] + red[1] + red[2] + red[3];
  float t2 = red[8] + red[9] + red[10] + red[11];
  float mean = t1 * (1.f / 256.f);
  float var = t2 * (1.f / 256.f) - mean * mean;
  float w = rsqrtf(var + 1e-5f);
  hio[tok * 256 + tid] = (v - mean) * w * gamma[tid] + beta[tid];
}

// ---------------- mean pool over S + classifier ----------------
__global__ void pool_cls_kernel(const float* __restrict__ h, const float* __restrict__ clsW,
                                const float* __restrict__ clsb, float* __restrict__ out) {
  __shared__ float pl[256];
  __shared__ float red[8];
  int b = blockIdx.x, tid = threadIdx.x, lane = tid & 63, wid = tid >> 6;
  float s = 0.f;
  for (int t = 0; t < 256; ++t) s += h[(b * 256 + t) * 256 + tid];
  pl[tid] = s * (1.f / 256.f);
  __syncthreads();
  for (int c = 0; c < 4; ++c) {
    float v = pl[tid] * clsW[tid * 4 + c];
#pragma unroll
    for (int off = 32; off; off >>= 1) v += __shfl_xor(v, off, 64);
    if (lane == 0) red[wid] = v;
    __syncthreads();
    if (tid == 0) out[b * 4 + c] = red[0] + red[1] + red[2] + red[3] + clsb[c];
    __syncthreads();
  }
}

extern "C" void kernel_launch(void* const* d_in, const int* in_sizes, int n_in,
                              void* d_out, int out_size, void* d_ws, size_t ws_size,
                              hipStream_t stream) {
  const int* x = (const int*)d_in[0];
  const float* token_emb = (const float*)d_in[1];
  const float* lstm_W = (const float*)d_in[2];
  const float* lstm_b = (const float*)d_in[3];
  const float* lstm_th = (const float*)d_in[4];
  const float* ln1_g = (const float*)d_in[5];
  const float* ln1_b = (const float*)d_in[6];
  const float* ln2_g = (const float*)d_in[7];
  const float* ln2_b = (const float*)d_in[8];
  const float* qkv_th = (const float*)d_in[9];
  const float* comb_W = (const float*)d_in[10];
  const float* comb_b = (const float*)d_in[11];
  const float* ffn_th = (const float*)d_in[12];
  const float* lin1_W = (const float*)d_in[13];
  const float* lin1_b = (const float*)d_in[14];
  const float* lin2_W = (const float*)d_in[15];
  const float* lin2_b = (const float*)d_in[16];
  const float* cls_W = (const float*)d_in[17];
  const float* cls_b = (const float*)d_in[18];

  float* ws = (float*)d_ws;
  typedef unsigned short ushort_t;
  // region 0 (1M f32): emb bf16 pre-loop; attn bf16 in-loop
  ushort_t* emb_b = (ushort_t*)ws;
  ushort_t* att_b = emb_b;
  // region 1 (4M f32): xw f32 pre-loop / ffh bf16 in-loop
  float* xw = ws + 1048576;
  ushort_t* ffh_b = (ushort_t*)xw;
  float* hb = ws + 5242880;   // 1M
  float* qq = ws + 6291456;   // 1M  (qq,kk,vv contiguous for fused qproj3)
  float* kk = ws + 7340032;   // 1M
  float* vv = ws + 8388608;   // 1M
  float* tmp = ws + 9437184;  // 1M; first 131072 u32 reused pre-loop for lstm packs
  unsigned* Wreg = (unsigned*)tmp;            // 98304 uints
  unsigned* WLg = (unsigned*)(tmp + 98304);   // 32768 uints
  ushort_t* ffq_b = (ushort_t*)(ws + 10485760);  // 1M ushort
  // weight packs bf16 (from 11.5M f32)
  ushort_t* wxt_b = (ushort_t*)(ws + 11534336);  // 262144 ushorts (4 gates x [256][256])
  ushort_t* cmb_b = wxt_b + 262144;              // 2 x 65536
  ushort_t* l1_b = cmb_b + 131072;               // 2 x 262144
  ushort_t* l2_b = l1_b + 524288;                // 2 x 262144

  const int LSTM_LDS = 131072 + 16384 + 4096 + 64 + 512;  // 152128 B
  const int ATT_LDS = (3 * 256 * 33 + 4 * 256) * 4;       // 105472 B
  (void)hipFuncSetAttribute(reinterpret_cast<const void*>(lstm_kernel),
                            hipFuncAttributeMaxDynamicSharedMemorySize, LSTM_LDS);
  (void)hipFuncSetAttribute(reinterpret_cast<const void*>(attn_kernel),
                            hipFuncAttributeMaxDynamicSharedMemorySize, ATT_LDS);

  embed_kernel<<<4096, 256, 0, stream>>>(x, token_emb, emb_b);
  pack_wreg_kernel<<<384, 256, 0, stream>>>(lstm_W, Wreg);
  pack_wl_kernel<<<128, 256, 0, stream>>>(lstm_W, WLg);
  // Wx^T per gate (z=4): K=256 rows of each [512][256] slice
  pack_bt<<<dim3(4, 4, 4), 256, 0, stream>>>(lstm_W, 256, 256, wxt_b, 131072, 65536);
  pack_bt<<<dim3(4, 4, 2), 256, 0, stream>>>(comb_W, 256, 256, cmb_b, 65536, 65536);
  pack_bt<<<dim3(16, 4, 2), 256, 0, stream>>>(lin1_W, 256, 1024, l1_b, 262144, 262144);
  pack_bt<<<dim3(4, 16, 2), 256, 0, stream>>>(lin2_W, 1024, 256, l2_b, 262144, 262144);

  // xw = emb @ Wx + lstm_b : M=4096 N=1024 K=256
  gemm_mfma<<<dim3(8, 32), 256, 0, stream>>>(emb_b, wxt_b, lstm_b,
                                             xw, nullptr, 4096, 1024, 256, 0);
  lstm_kernel<<<16, 1024, LSTM_LDS, stream>>>(Wreg, WLg, lstm_th, xw, hb);
  pe_add_kernel<<<4096, 256, 0, stream>>>(hb);

  for (int l = 0; l < 2; ++l) {
    qproj3_kernel<<<dim3(4096, 3), 256, 0, stream>>>(hb, qkv_th + l * 768, qq);
    attn_kernel<<<dim3(8, 16), 256, ATT_LDS, stream>>>(qq, kk, vv, att_b);
    gemm_mfma<<<dim3(2, 32), 256, 0, stream>>>(att_b, cmb_b + l * 65536, comb_b + l * 256,
                                               tmp, nullptr, 4096, 256, 256, 0);
    ln_kernel<<<4096, 256, 0, stream>>>(hb, tmp, ln1_g + l * 256, ln1_b + l * 256);
    qproj_bf_kernel<<<4096, 256, 0, stream>>>(hb, ffn_th + l * 256, ffq_b);
    gemm_mfma<<<dim3(8, 32), 256, 0, stream>>>(ffq_b, l1_b + l * 262144, lin1_b + l * 1024,
                                               nullptr, ffh_b, 4096, 1024, 256, 1);
    gemm_mfma<<<dim3(2, 32), 256, 0, stream>>>(ffh_b, l2_b + l * 262144, lin2_b + l * 256,
                                               tmp, nullptr, 4096, 256, 1024, 0);
    ln_kernel<<<4096, 256, 0, stream>>>(hb, tmp, ln2_g + l * 256, ln2_b + l * 256);
  }

  pool_cls_kernel<<<16, 256, 0, stream>>>(hb, cls_W, cls_b, (float*)d_out);
}

// Round 6
// 1272.526 us; speedup vs baseline: 3.2989x; 1.1216x over previous
//
#include <hip/hip_runtime.h>
#include <hip/hip_bf16.h>

// Problem constants: B=16, S=256, V=32000, E=256, H=8, L=2, FFN=1024, NC=4, DK=32, NQ=256

typedef __attribute__((ext_vector_type(8))) short bf8v;   // 8 bf16 in 4 VGPRs
typedef __attribute__((ext_vector_type(4))) float f4v;    // MFMA accumulator
#define MFMA16 __builtin_amdgcn_mfma_f32_16x16x32_bf16

__device__ __forceinline__ unsigned short f2bf(float f) {
  unsigned u = __builtin_bit_cast(unsigned, f);
  u += 0x7fffu + ((u >> 16) & 1u);
  return (unsigned short)(u >> 16);
}
__device__ __forceinline__ float rcp_f(float x) { return __builtin_amdgcn_rcpf(x); }
__device__ __forceinline__ float sigm(float x) { return rcp_f(1.f + __expf(-x)); }
__device__ __forceinline__ float tanh_f(float x) { return 1.f - 2.f * rcp_f(__expf(2.f * x) + 1.f); }

// v_dot2_f32_bf16: acc += a.x*b.x + a.y*b.y  (packed bf16 pairs in uint)
#define DOT2BF(acc, a, b) \
  asm("v_dot2_f32_bf16 %0, %1, %2, %0" : "+v"(acc) : "v"(a), "v"(b))

// ---------------- embedding gather -> bf16 ----------------
__global__ void embed_kernel(const int* __restrict__ x, const float* __restrict__ tab,
                             unsigned short* __restrict__ eb) {
  int tok = blockIdx.x, tid = threadIdx.x;
  eb[tok * 256 + tid] = f2bf(tab[x[tok] * 256 + tid]);
}

// ---- transpose to bf16: W [K][N] f32 -> T[n][k] bf16 ; blockIdx.z batches slices ----
__global__ void pack_bt(const float* __restrict__ W, int K, int N,
                        unsigned short* __restrict__ Th, long wz, long tz) {
  __shared__ float tile[64][65];
  W += (long)blockIdx.z * wz;
  Th += (long)blockIdx.z * tz;
  int n0 = blockIdx.x * 64, k0 = blockIdx.y * 64;
  int tid = threadIdx.x, tx = tid & 63, ty = tid >> 6;
  for (int r = ty; r < 64; r += 4) tile[r][tx] = W[(k0 + r) * N + n0 + tx];
  __syncthreads();
  for (int r = ty; r < 64; r += 4) {
    Th[(n0 + r) * K + k0 + tx] = f2bf(tile[tx][r]);  // = W[k0+tx][n0+r]
  }
}

// ---- pack h-part of gates 0..2 as bf16 d-pairs; half-split (s=0..1, 128 d each) ----
// uint o = ((gs*16 + i4)*256 + q)*4 + c ; gs=gi*2+s, pair i=i4*4+c, d=s*128+2i
__global__ void pack_wreg_kernel(const float* __restrict__ lstmW, unsigned* __restrict__ Wreg) {
  int o = blockIdx.x * 256 + threadIdx.x;  // < 98304
  int c = o & 3;
  int q = (o >> 2) & 255;
  int i4 = (o >> 10) & 15;
  int gs = o >> 14;  // 0..5
  int gi = gs >> 1, s = gs & 1;
  int i = i4 * 4 + c;
  int d = s * 128 + 2 * i;
  unsigned lo = f2bf(lstmW[(gi * 512 + 256 + d) * 256 + q]);
  unsigned hi = f2bf(lstmW[(gi * 512 + 256 + d + 1) * 256 + q]);
  Wreg[o] = lo | (hi << 16);
}

// ---- pack h-part of gate 3 as bf16 d-pairs for LDS ----
__global__ void pack_wl_kernel(const float* __restrict__ lstmW, unsigned* __restrict__ WLg) {
  int o = blockIdx.x * 256 + threadIdx.x;  // < 32768
  int c = o & 3;
  int q = (o >> 2) & 255;
  int p4 = o >> 10;  // 0..31
  int d = 2 * (p4 * 4 + c);
  unsigned lo = f2bf(lstmW[(3 * 512 + 256 + d) * 256 + q]);
  unsigned hi = f2bf(lstmW[(3 * 512 + 256 + d + 1) * 256 + q]);
  WLg[o] = lo | (hi << 16);
}

// ---------------- MFMA GEMM, single-pass bf16: C = A*B + bias ----------------
__global__ void __launch_bounds__(256) gemm_mfma(const unsigned short* __restrict__ A,
                                                 const unsigned short* __restrict__ B,
                                                 const float* __restrict__ bias,
                                                 float* __restrict__ Cf,
                                                 unsigned short* __restrict__ Cb,
                                                 int M, int N, int K, int mode) {
  __shared__ unsigned short As[128 * 40];
  __shared__ unsigned short Bs[128 * 40];

  const int tid = threadIdx.x;
  const int lane = tid & 63;
  const int wid = tid >> 6;
  const int wr = wid >> 1, wc = wid & 1;
  const int bm = blockIdx.y * 128, bn = blockIdx.x * 128;

  const int srow = tid >> 2;
  const int scol = (tid & 3) * 8;

  f4v acc[4][4] = {};

  for (int kt = 0; kt < K; kt += 32) {
#pragma unroll
    for (int p = 0; p < 2; ++p) {
      int r = srow + p * 64;
      *(uint4*)(&As[r * 40 + scol]) = *(const uint4*)(&A[(bm + r) * K + kt + scol]);
      *(uint4*)(&Bs[r * 40 + scol]) = *(const uint4*)(&B[(bn + r) * K + kt + scol]);
    }
    __syncthreads();

    bf8v a[4], b[4];
    const int kq = (lane >> 4) * 8;
#pragma unroll
    for (int f = 0; f < 4; ++f) {
      a[f] = *(const bf8v*)(&As[(wr * 64 + f * 16 + (lane & 15)) * 40 + kq]);
      b[f] = *(const bf8v*)(&Bs[(wc * 64 + f * 16 + (lane & 15)) * 40 + kq]);
    }
#pragma unroll
    for (int fm = 0; fm < 4; ++fm)
#pragma unroll
      for (int fn = 0; fn < 4; ++fn)
        acc[fm][fn] = MFMA16(a[fm], b[fn], acc[fm][fn], 0, 0, 0);
    __syncthreads();
  }

#pragma unroll
  for (int fm = 0; fm < 4; ++fm)
#pragma unroll
    for (int fn = 0; fn < 4; ++fn) {
      int c = bn + wc * 64 + fn * 16 + (lane & 15);
      int r0 = bm + wr * 64 + fm * 16 + ((lane >> 4) << 2);
      float bv = bias[c];
#pragma unroll
      for (int j = 0; j < 4; ++j) {
        float v = acc[fm][fn][j] + bv;
        if (mode == 1) {
          Cb[(r0 + j) * N + c] = f2bf(fmaxf(v, 0.f));
        } else {
          Cf[(r0 + j) * N + c] = v;
        }
      }
    }
}

// ---------------- QLSTM: one block per batch; 512 threads; half d-split ----------------
// Thread t: q=t&255, s=t>>8. Gates 0..2 half-columns in 48 uint4 regs (192 VGPR),
// gate 3 in LDS. amdgpu_waves_per_eu(2,2) forces the 256-VGPR budget (2 waves/SIMD).
__global__ void
__attribute__((amdgpu_flat_work_group_size(512, 512), amdgpu_waves_per_eu(2, 2)))
lstm_kernel(const unsigned* __restrict__ Wreg,
            const unsigned* __restrict__ WLg,
            const float* __restrict__ lstmTh,
            const float* __restrict__ xw,
            float* __restrict__ hb) {
  extern __shared__ char smem[];
  unsigned* WL = (unsigned*)smem;               // [32][256] uint4 rows (131072 B)
  float* part = (float*)(smem + 131072);        // [8][256]  (g*2+s, q)
  float* qv = part + 2048;                      // [1024]  segment-scan values, gate-major
  float* wtot = qv + 1024;                      // [16]  (wave, slot)
  unsigned* hp = (unsigned*)(wtot + 16);        // [128] packed bf16 h pairs

  const int t = threadIdx.x;
  const int b = blockIdx.x;
  const int q = t & 255;
  const int s = t >> 8;
  const int lane = t & 63;
  const int w = t >> 6;  // wave 0..7

  {
    const uint4* src = (const uint4*)WLg;
    uint4* dst = (uint4*)WL;
    for (int j = t; j < 8192; j += 512) dst[j] = src[j];
  }
  const uint4* Wreg4 = (const uint4*)Wreg;
  uint4 wreg[48];
#pragma unroll
  for (int j = 0; j < 48; ++j) {
    int gi = j >> 4, i4 = j & 15;
    wreg[j] = Wreg4[((gi * 2 + s) * 16 + i4) * 256 + q];
  }
  // pin in VGPRs: an asm result cannot be rematerialized as a sunk load
#pragma unroll
  for (int j = 0; j < 48; ++j) {
    asm volatile("" : "+v"(wreg[j].x), "+v"(wreg[j].y), "+v"(wreg[j].z), "+v"(wreg[j].w));
  }
  const float thA = lstmTh[t];          // gate s, col q
  const float thB = lstmTh[512 + t];    // gate s+2, col q
  float cx = 0.f;                       // valid for t<256 (q-owner)
  if (t < 128) hp[t] = 0u;
  __syncthreads();

  const int xbase = (b << 8) * 1024;
  const uint4* WL4 = (const uint4*)WL;
  const uint4* hp4 = (const uint4*)hp;

  float xa = xw[xbase + t];
  float xb = xw[xbase + 512 + t];

  for (int st = 0; st < 256; ++st) {
    // prefetch next step's xw (consumed next iteration; hides HBM latency)
    int nx = (st < 255) ? st + 1 : 255;
    float xa_n = xw[xbase + nx * 1024 + t];
    float xb_n = xw[xbase + nx * 1024 + 512 + t];

    // ---- GEMV half-dots: 4 gates, 128 d each (64 pairs = 16 uint4) ----
    float a0 = 0.f, a1 = 0.f, a2 = 0.f, a3 = 0.f;
#pragma unroll
    for (int i4 = 0; i4 < 16; ++i4) {
      uint4 hh = hp4[(s << 4) + i4];
      uint4 w3 = WL4[((s << 4) + i4) * 256 + q];
      uint4 w0 = wreg[i4];
      uint4 w1 = wreg[16 + i4];
      uint4 w2 = wreg[32 + i4];
      DOT2BF(a0, w0.x, hh.x); DOT2BF(a0, w0.y, hh.y);
      DOT2BF(a0, w0.z, hh.z); DOT2BF(a0, w0.w, hh.w);
      DOT2BF(a1, w1.x, hh.x); DOT2BF(a1, w1.y, hh.y);
      DOT2BF(a1, w1.z, hh.z); DOT2BF(a1, w1.w, hh.w);
      DOT2BF(a2, w2.x, hh.x); DOT2BF(a2, w2.y, hh.y);
      DOT2BF(a2, w2.z, hh.z); DOT2BF(a2, w2.w, hh.w);
      DOT2BF(a3, w3.x, hh.x); DOT2BF(a3, w3.y, hh.y);
      DOT2BF(a3, w3.z, hh.z); DOT2BF(a3, w3.w, hh.w);
    }
    part[(0 * 2 + s) * 256 + q] = a0;
    part[(1 * 2 + s) * 256 + q] = a1;
    part[(2 * 2 + s) * 256 + q] = a2;
    part[(3 * 2 + s) * 256 + q] = a3;
    __syncthreads();  // barrier 1: partials ready

    // ---- finalize z; cos; segment scan (wave = one 64-col segment) ----
    int gA = s, gB = s + 2;
    float zA = part[(gA * 2 + 0) * 256 + q] + part[(gA * 2 + 1) * 256 + q] + xa + thA;
    float zB = part[(gB * 2 + 0) * 256 + q] + part[(gB * 2 + 1) * 256 + q] + xb + thB;
    float vA = __cosf(zA);
    float vB = __cosf(zB);
#pragma unroll
    for (int off = 1; off < 64; off <<= 1) {
      float oA = __shfl_up(vA, off, 64);
      float oB = __shfl_up(vB, off, 64);
      if (lane >= off) { vA *= oA; vB *= oB; }
    }
    if (lane == 63) { wtot[w * 2] = vA; wtot[w * 2 + 1] = vB; }
    qv[s * 256 + q] = vA;        // gate s     (segment-local scan)
    qv[512 + s * 256 + q] = vB;  // gate s+2
    __syncthreads();  // barrier 2: qv + wtot ready

    // ---- combine (threads 0..255 own column q); apply segment prefixes here ----
    if (t < 256) {
      int j = q >> 6;  // segment index == wave-within-gate, uniform per wave
      float p0 = 1.f, p1 = 1.f, p2 = 1.f, p3 = 1.f;
      for (int k = 0; k < j; ++k) {
        p0 *= wtot[2 * k];            // gate0: slot A, waves 0..3
        p1 *= wtot[2 * (4 + k)];      // gate1: slot A, waves 4..7
        p2 *= wtot[2 * k + 1];        // gate2: slot B, waves 0..3
        p3 *= wtot[2 * (4 + k) + 1];  // gate3: slot B, waves 4..7
      }
      float fg = sigm(qv[t] * p0);
      float ig = sigm(qv[256 + t] * p1);
      float gg = tanh_f(qv[512 + t] * p2);
      float og = sigm(qv[768 + t] * p3);
      cx = fg * cx + ig * gg;
      float hv = og * tanh_f(cx);
      hb[((b << 8) + st) * 256 + t] = hv;
      float nb = __shfl_xor(hv, 1, 64);
      if ((t & 1) == 0) hp[t >> 1] = (unsigned)f2bf(hv) | ((unsigned)f2bf(nb) << 16);
    }
    __syncthreads();  // barrier 3: hp ready
    xa = xa_n;
    xb = xb_n;
  }
}

// ---------------- h += sinusoidal PE ----------------
__global__ void pe_add_kernel(float* __restrict__ h) {
  int tok = blockIdx.x, tid = threadIdx.x;
  int s = tok & 255;
  int j = tid >> 1;
  float div = __expf((float)j * -0.07195578415622253f);
  float ang = (float)s * div;
  float pe = (tid & 1) ? __cosf(ang) : __sinf(ang);
  h[tok * 256 + tid] += pe;
}

// ---------------- qproj x3 fused (f32 out, contiguous q/k/v buffers) ----------------
__global__ void qproj3_kernel(const float* __restrict__ hin, const float* __restrict__ thetas,
                              float* __restrict__ outbase) {
  __shared__ float wtot[4];
  int tok = blockIdx.x, y = blockIdx.y;
  int tid = threadIdx.x, lane = tid & 63, wid = tid >> 6;
  const float* theta = thetas + y * 256;
  float* out = outbase + (long)y * 1048576;
  float v = __cosf(hin[tok * 256 + tid] + theta[tid]);
#pragma unroll
  for (int off = 1; off < 64; off <<= 1) {
    float o = __shfl_up(v, off, 64);
    if (lane >= off) v *= o;
  }
  if (lane == 63) wtot[wid] = v;
  __syncthreads();
  float pre = 1.f;
  for (int w = 0; w < wid; ++w) pre *= wtot[w];
  out[tok * 256 + tid] = v * pre;
}

// ---------------- qproj -> bf16 (FFN input) ----------------
__global__ void qproj_bf_kernel(const float* __restrict__ hin, const float* __restrict__ theta,
                                unsigned short* __restrict__ outb) {
  __shared__ float wtot[4];
  int tok = blockIdx.x, tid = threadIdx.x, lane = tid & 63, wid = tid >> 6;
  float v = __cosf(hin[tok * 256 + tid] + theta[tid]);
#pragma unroll
  for (int off = 1; off < 64; off <<= 1) {
    float o = __shfl_up(v, off, 64);
    if (lane >= off) v *= o;
  }
  if (lane == 63) wtot[wid] = v;
  __syncthreads();
  float pre = 1.f;
  for (int w = 0; w < wid; ++w) pre *= wtot[w];
  outb[tok * 256 + tid] = f2bf(v * pre);
}

// ---------------- attention: block per (head,batch); vectorized LDS ----------------
// Q,K at stride 36 (float4-aligned); V staged d-major [32][260] so PV is float4.
__global__ void __launch_bounds__(256, 1) attn_kernel(const float* __restrict__ qb,
                                                      const float* __restrict__ kb,
                                                      const float* __restrict__ vb,
                                                      unsigned short* __restrict__ outb) {
  extern __shared__ float sm[];
  float* Qs = sm;                 // [256][36]
  float* Ks = Qs + 256 * 36;      // [256][36]
  float* Vs = Ks + 256 * 36;      // [32][260]  d-major
  float* ps = Vs + 32 * 260;      // [4][256]
  int hd = blockIdx.x, b = blockIdx.y;
  int tid = threadIdx.x, lane = tid & 63, wid = tid >> 6;
  const float scale = 0.17677669529663687f;  // 1/sqrt(32)

  for (int i = tid; i < 256 * 32; i += 256) {
    int r = i >> 5, d = i & 31;
    int src = (b * 256 + r) * 256 + hd * 32 + d;
    Qs[r * 36 + d] = qb[src];
    Ks[r * 36 + d] = kb[src];
    Vs[d * 260 + r] = vb[src];
  }
  __syncthreads();

  float* pw = ps + wid * 256;
  for (int r = wid; r < 256; r += 4) {
    float4 qreg[8];
    const float4* qrow = (const float4*)(Qs + r * 36);
#pragma unroll
    for (int i = 0; i < 8; ++i) qreg[i] = qrow[i];
    float s[4];
#pragma unroll
    for (int j = 0; j < 4; ++j) {
      int k = lane + 64 * j;
      const float4* kr = (const float4*)(Ks + k * 36);
      float a = 0.f;
#pragma unroll
      for (int i = 0; i < 8; ++i) {
        float4 kv = kr[i];
        a += qreg[i].x * kv.x + qreg[i].y * kv.y + qreg[i].z * kv.z + qreg[i].w * kv.w;
      }
      s[j] = a * scale;
    }
    float m = fmaxf(fmaxf(s[0], s[1]), fmaxf(s[2], s[3]));
#pragma unroll
    for (int off = 32; off; off >>= 1) m = fmaxf(m, __shfl_xor(m, off, 64));
    float p[4], sum = 0.f;
#pragma unroll
    for (int j = 0; j < 4; ++j) { p[j] = __expf(s[j] - m); sum += p[j]; }
#pragma unroll
    for (int off = 32; off; off >>= 1) sum += __shfl_xor(sum, off, 64);
    float inv = rcp_f(sum);
#pragma unroll
    for (int j = 0; j < 4; ++j) pw[lane + 64 * j] = p[j] * inv;
    int d = lane & 31, half = lane >> 5;
    const float4* pv = (const float4*)(pw + half * 128);
    const float4* v4 = (const float4*)(Vs + d * 260 + half * 128);
    float a = 0.f;
#pragma unroll
    for (int i = 0; i < 32; ++i) {
      float4 pp = pv[i];
      float4 vv = v4[i];
      a += pp.x * vv.x + pp.y * vv.y + pp.z * vv.z + pp.w * vv.w;
    }
    a += __shfl_down(a, 32, 64);
    if (lane < 32) outb[(b * 256 + r) * 256 + hd * 32 + d] = f2bf(a);
  }
}

// ---------------- layernorm(h + delta) -> h ----------------
__global__ void ln_kernel(float* __restrict__ hio, const float* __restrict__ delta,
                          const float* __restrict__ gamma, const float* __restrict__ beta) {
  __shared__ float red[16];
  int tok = blockIdx.x, tid = threadIdx.x, lane = tid & 63, wid = tid >> 6;
  float v = hio[tok * 256 + tid] + delta[tok * 256 + tid];
  float s1 = v, s2 = v * v;
#pragma unroll
  for (int off = 32; off; off >>= 1) {
    s1 += __shfl_xor(s1, off, 64);
    s2 += __shfl_xor(s2, off, 64);
  }
  if (lane == 0) { red[wid] = s1; red[wid + 8] = s2; }
  __syncthreads();
  float t1 = red[0] + red[1] + red[2] + red[3];
  float t2 = red[8] + red[9] + red[10] + red[11];
  float mean = t1 * (1.f / 256.f);
  float var = t2 * (1.f / 256.f) - mean * mean;
  float w = rsqrtf(var + 1e-5f);
  hio[tok * 256 + tid] = (v - mean) * w * gamma[tid] + beta[tid];
}

// ---------------- mean pool over S + classifier ----------------
__global__ void pool_cls_kernel(const float* __restrict__ h, const float* __restrict__ clsW,
                                const float* __restrict__ clsb, float* __restrict__ out) {
  __shared__ float pl[256];
  __shared__ float red[8];
  int b = blockIdx.x, tid = threadIdx.x, lane = tid & 63, wid = tid >> 6;
  float s = 0.f;
  for (int t = 0; t < 256; ++t) s += h[(b * 256 + t) * 256 + tid];
  pl[tid] = s * (1.f / 256.f);
  __syncthreads();
  for (int c = 0; c < 4; ++c) {
    float v = pl[tid] * clsW[tid * 4 + c];
#pragma unroll
    for (int off = 32; off; off >>= 1) v += __shfl_xor(v, off, 64);
    if (lane == 0) red[wid] = v;
    __syncthreads();
    if (tid == 0) out[b * 4 + c] = red[0] + red[1] + red[2] + red[3] + clsb[c];
    __syncthreads();
  }
}

extern "C" void kernel_launch(void* const* d_in, const int* in_sizes, int n_in,
                              void* d_out, int out_size, void* d_ws, size_t ws_size,
                              hipStream_t stream) {
  const int* x = (const int*)d_in[0];
  const float* token_emb = (const float*)d_in[1];
  const float* lstm_W = (const float*)d_in[2];
  const float* lstm_b = (const float*)d_in[3];
  const float* lstm_th = (const float*)d_in[4];
  const float* ln1_g = (const float*)d_in[5];
  const float* ln1_b = (const float*)d_in[6];
  const float* ln2_g = (const float*)d_in[7];
  const float* ln2_b = (const float*)d_in[8];
  const float* qkv_th = (const float*)d_in[9];
  const float* comb_W = (const float*)d_in[10];
  const float* comb_b = (const float*)d_in[11];
  const float* ffn_th = (const float*)d_in[12];
  const float* lin1_W = (const float*)d_in[13];
  const float* lin1_b = (const float*)d_in[14];
  const float* lin2_W = (const float*)d_in[15];
  const float* lin2_b = (const float*)d_in[16];
  const float* cls_W = (const float*)d_in[17];
  const float* cls_b = (const float*)d_in[18];

  float* ws = (float*)d_ws;
  typedef unsigned short ushort_t;
  ushort_t* emb_b = (ushort_t*)ws;       // 1M f32 region: emb bf16 pre-loop / attn bf16 in-loop
  ushort_t* att_b = emb_b;
  float* xw = ws + 1048576;              // 4M f32: xw pre-loop / ffh bf16 in-loop
  ushort_t* ffh_b = (ushort_t*)xw;
  float* hb = ws + 5242880;   // 1M
  float* qq = ws + 6291456;   // 1M  (qq,kk,vv contiguous for fused qproj3)
  float* kk = ws + 7340032;   // 1M
  float* vv = ws + 8388608;   // 1M
  float* tmp = ws + 9437184;  // 1M; first 131072 u32 reused pre-loop for lstm packs
  unsigned* Wreg = (unsigned*)tmp;            // 98304 uints
  unsigned* WLg = (unsigned*)(tmp + 98304);   // 32768 uints
  ushort_t* ffq_b = (ushort_t*)(ws + 10485760);  // 1M ushort
  ushort_t* wxt_b = (ushort_t*)(ws + 11534336);  // 262144 (4 gates x [256][256])
  ushort_t* cmb_b = wxt_b + 262144;              // 2 x 65536
  ushort_t* l1_b = cmb_b + 131072;               // 2 x 262144
  ushort_t* l2_b = l1_b + 524288;                // 2 x 262144

  const int LSTM_LDS = 131072 + 8192 + 4096 + 64 + 512;            // 143936 B
  const int ATT_LDS = (256 * 36 * 2 + 32 * 260 + 4 * 256) * 4;     // 111104 B
  (void)hipFuncSetAttribute(reinterpret_cast<const void*>(lstm_kernel),
                            hipFuncAttributeMaxDynamicSharedMemorySize, LSTM_LDS);
  (void)hipFuncSetAttribute(reinterpret_cast<const void*>(attn_kernel),
                            hipFuncAttributeMaxDynamicSharedMemorySize, ATT_LDS);

  embed_kernel<<<4096, 256, 0, stream>>>(x, token_emb, emb_b);
  pack_wreg_kernel<<<384, 256, 0, stream>>>(lstm_W, Wreg);
  pack_wl_kernel<<<128, 256, 0, stream>>>(lstm_W, WLg);
  pack_bt<<<dim3(4, 4, 4), 256, 0, stream>>>(lstm_W, 256, 256, wxt_b, 131072, 65536);
  pack_bt<<<dim3(4, 4, 2), 256, 0, stream>>>(comb_W, 256, 256, cmb_b, 65536, 65536);
  pack_bt<<<dim3(16, 4, 2), 256, 0, stream>>>(lin1_W, 256, 1024, l1_b, 262144, 262144);
  pack_bt<<<dim3(4, 16, 2), 256, 0, stream>>>(lin2_W, 1024, 256, l2_b, 262144, 262144);

  // xw = emb @ Wx + lstm_b : M=4096 N=1024 K=256
  gemm_mfma<<<dim3(8, 32), 256, 0, stream>>>(emb_b, wxt_b, lstm_b,
                                             xw, nullptr, 4096, 1024, 256, 0);
  lstm_kernel<<<16, 512, LSTM_LDS, stream>>>(Wreg, WLg, lstm_th, xw, hb);
  pe_add_kernel<<<4096, 256, 0, stream>>>(hb);

  for (int l = 0; l < 2; ++l) {
    qproj3_kernel<<<dim3(4096, 3), 256, 0, stream>>>(hb, qkv_th + l * 768, qq);
    attn_kernel<<<dim3(8, 16), 256, ATT_LDS, stream>>>(qq, kk, vv, att_b);
    gemm_mfma<<<dim3(2, 32), 256, 0, stream>>>(att_b, cmb_b + l * 65536, comb_b + l * 256,
                                               tmp, nullptr, 4096, 256, 256, 0);
    ln_kernel<<<4096, 256, 0, stream>>>(hb, tmp, ln1_g + l * 256, ln1_b + l * 256);
    qproj_bf_kernel<<<4096, 256, 0, stream>>>(hb, ffn_th + l * 256, ffq_b);
    gemm_mfma<<<dim3(8, 32), 256, 0, stream>>>(ffq_b, l1_b + l * 262144, lin1_b + l * 1024,
                                               nullptr, ffh_b, 4096, 1024, 256, 1);
    gemm_mfma<<<dim3(2, 32), 256, 0, stream>>>(ffh_b, l2_b + l * 262144, lin2_b + l * 256,
                                               tmp, nullptr, 4096, 256, 1024, 0);
    ln_kernel<<<4096, 256, 0, stream>>>(hb, tmp, ln2_g + l * 256, ln2_b + l * 256);
  }

  pool_cls_kernel<<<16, 256, 0, stream>>>(hb, cls_W, cls_b, (float*)d_out);
}

// Round 7
// 1227.279 us; speedup vs baseline: 3.4206x; 1.0369x over previous
//
#include <hip/hip_runtime.h>
#include <hip/hip_bf16.h>

// Problem constants: B=16, S=256, V=32000, E=256, H=8, L=2, FFN=1024, NC=4, DK=32, NQ=256

typedef __attribute__((ext_vector_type(8))) short bf8v;   // 8 bf16 in 4 VGPRs
typedef __attribute__((ext_vector_type(4))) float f4v;    // MFMA accumulator
#define MFMA16 __builtin_amdgcn_mfma_f32_16x16x32_bf16

__device__ __forceinline__ unsigned short f2bf(float f) {
  unsigned u = __builtin_bit_cast(unsigned, f);
  u += 0x7fffu + ((u >> 16) & 1u);
  return (unsigned short)(u >> 16);
}
__device__ __forceinline__ float rcp_f(float x) { return __builtin_amdgcn_rcpf(x); }
__device__ __forceinline__ float sigm(float x) { return rcp_f(1.f + __expf(-x)); }
__device__ __forceinline__ float tanh_f(float x) { return 1.f - 2.f * rcp_f(__expf(2.f * x) + 1.f); }

// v_dot2_f32_bf16: acc += a.x*b.x + a.y*b.y  (packed bf16 pairs in uint)
#define DOT2BF(acc, a, b) \
  asm("v_dot2_f32_bf16 %0, %1, %2, %0" : "+v"(acc) : "v"(a), "v"(b))

// ---------------- embedding gather -> bf16 ----------------
__global__ void embed_kernel(const int* __restrict__ x, const float* __restrict__ tab,
                             unsigned short* __restrict__ eb) {
  int tok = blockIdx.x, tid = threadIdx.x;
  eb[tok * 256 + tid] = f2bf(tab[x[tok] * 256 + tid]);
}

// ---- transpose to bf16: W [K][N] f32 -> T[n][k] bf16 ; blockIdx.z batches slices ----
__global__ void pack_bt(const float* __restrict__ W, int K, int N,
                        unsigned short* __restrict__ Th, long wz, long tz) {
  __shared__ float tile[64][65];
  W += (long)blockIdx.z * wz;
  Th += (long)blockIdx.z * tz;
  int n0 = blockIdx.x * 64, k0 = blockIdx.y * 64;
  int tid = threadIdx.x, tx = tid & 63, ty = tid >> 6;
  for (int r = ty; r < 64; r += 4) tile[r][tx] = W[(k0 + r) * N + n0 + tx];
  __syncthreads();
  for (int r = ty; r < 64; r += 4) {
    Th[(n0 + r) * K + k0 + tx] = f2bf(tile[tx][r]);  // = W[k0+tx][n0+r]
  }
}

// ---- pack h-part of gates 0..2 as bf16 d-pairs; half-split (s=0..1, 128 d each) ----
// uint o = ((gs*16 + i4)*256 + q)*4 + c ; gs=gi*2+s, pair i=i4*4+c, d=s*128+2i
__global__ void pack_wreg_kernel(const float* __restrict__ lstmW, unsigned* __restrict__ Wreg) {
  int o = blockIdx.x * 256 + threadIdx.x;  // < 98304
  int c = o & 3;
  int q = (o >> 2) & 255;
  int i4 = (o >> 10) & 15;
  int gs = o >> 14;  // 0..5
  int gi = gs >> 1, s = gs & 1;
  int i = i4 * 4 + c;
  int d = s * 128 + 2 * i;
  unsigned lo = f2bf(lstmW[(gi * 512 + 256 + d) * 256 + q]);
  unsigned hi = f2bf(lstmW[(gi * 512 + 256 + d + 1) * 256 + q]);
  Wreg[o] = lo | (hi << 16);
}

// ---- pack h-part of gate 3 as bf16 d-pairs for LDS ----
__global__ void pack_wl_kernel(const float* __restrict__ lstmW, unsigned* __restrict__ WLg) {
  int o = blockIdx.x * 256 + threadIdx.x;  // < 32768
  int c = o & 3;
  int q = (o >> 2) & 255;
  int p4 = o >> 10;  // 0..31
  int d = 2 * (p4 * 4 + c);
  unsigned lo = f2bf(lstmW[(3 * 512 + 256 + d) * 256 + q]);
  unsigned hi = f2bf(lstmW[(3 * 512 + 256 + d + 1) * 256 + q]);
  WLg[o] = lo | (hi << 16);
}

// ---------------- MFMA GEMM, single-pass bf16: C = A*B + bias ----------------
__global__ void __launch_bounds__(256) gemm_mfma(const unsigned short* __restrict__ A,
                                                 const unsigned short* __restrict__ B,
                                                 const float* __restrict__ bias,
                                                 float* __restrict__ Cf,
                                                 unsigned short* __restrict__ Cb,
                                                 int M, int N, int K, int mode) {
  __shared__ unsigned short As[128 * 40];
  __shared__ unsigned short Bs[128 * 40];

  const int tid = threadIdx.x;
  const int lane = tid & 63;
  const int wid = tid >> 6;
  const int wr = wid >> 1, wc = wid & 1;
  const int bm = blockIdx.y * 128, bn = blockIdx.x * 128;

  const int srow = tid >> 2;
  const int scol = (tid & 3) * 8;

  f4v acc[4][4] = {};

  for (int kt = 0; kt < K; kt += 32) {
#pragma unroll
    for (int p = 0; p < 2; ++p) {
      int r = srow + p * 64;
      *(uint4*)(&As[r * 40 + scol]) = *(const uint4*)(&A[(bm + r) * K + kt + scol]);
      *(uint4*)(&Bs[r * 40 + scol]) = *(const uint4*)(&B[(bn + r) * K + kt + scol]);
    }
    __syncthreads();

    bf8v a[4], b[4];
    const int kq = (lane >> 4) * 8;
#pragma unroll
    for (int f = 0; f < 4; ++f) {
      a[f] = *(const bf8v*)(&As[(wr * 64 + f * 16 + (lane & 15)) * 40 + kq]);
      b[f] = *(const bf8v*)(&Bs[(wc * 64 + f * 16 + (lane & 15)) * 40 + kq]);
    }
#pragma unroll
    for (int fm = 0; fm < 4; ++fm)
#pragma unroll
      for (int fn = 0; fn < 4; ++fn)
        acc[fm][fn] = MFMA16(a[fm], b[fn], acc[fm][fn], 0, 0, 0);
    __syncthreads();
  }

#pragma unroll
  for (int fm = 0; fm < 4; ++fm)
#pragma unroll
    for (int fn = 0; fn < 4; ++fn) {
      int c = bn + wc * 64 + fn * 16 + (lane & 15);
      int r0 = bm + wr * 64 + fm * 16 + ((lane >> 4) << 2);
      float bv = bias[c];
#pragma unroll
      for (int j = 0; j < 4; ++j) {
        float v = acc[fm][fn][j] + bv;
        if (mode == 1) {
          Cb[(r0 + j) * N + c] = f2bf(fmaxf(v, 0.f));
        } else {
          Cf[(r0 + j) * N + c] = v;
        }
      }
    }
}

// ---------------- QLSTM: one block per batch; 512 threads; half d-split ----------------
// Gates 0..2 half-columns in 48 NAMED uint4 locals (192 VGPR) -- no array, so no
// alloca/scratch path exists; gate 3 in LDS. waves_per_eu(2,2) => 256-VGPR budget.
#define LOADW(gi)                                                          \
  w##gi##_0 = Wreg4[((gi * 2 + s) * 16 + 0) * 256 + q];                    \
  w##gi##_1 = Wreg4[((gi * 2 + s) * 16 + 1) * 256 + q];                    \
  w##gi##_2 = Wreg4[((gi * 2 + s) * 16 + 2) * 256 + q];                    \
  w##gi##_3 = Wreg4[((gi * 2 + s) * 16 + 3) * 256 + q];                    \
  w##gi##_4 = Wreg4[((gi * 2 + s) * 16 + 4) * 256 + q];                    \
  w##gi##_5 = Wreg4[((gi * 2 + s) * 16 + 5) * 256 + q];                    \
  w##gi##_6 = Wreg4[((gi * 2 + s) * 16 + 6) * 256 + q];                    \
  w##gi##_7 = Wreg4[((gi * 2 + s) * 16 + 7) * 256 + q];                    \
  w##gi##_8 = Wreg4[((gi * 2 + s) * 16 + 8) * 256 + q];                    \
  w##gi##_9 = Wreg4[((gi * 2 + s) * 16 + 9) * 256 + q];                    \
  w##gi##_10 = Wreg4[((gi * 2 + s) * 16 + 10) * 256 + q];                  \
  w##gi##_11 = Wreg4[((gi * 2 + s) * 16 + 11) * 256 + q];                  \
  w##gi##_12 = Wreg4[((gi * 2 + s) * 16 + 12) * 256 + q];                  \
  w##gi##_13 = Wreg4[((gi * 2 + s) * 16 + 13) * 256 + q];                  \
  w##gi##_14 = Wreg4[((gi * 2 + s) * 16 + 14) * 256 + q];                  \
  w##gi##_15 = Wreg4[((gi * 2 + s) * 16 + 15) * 256 + q];

#define CHUNK(i4)                                                          \
  {                                                                        \
    uint4 hh = hp4[(s << 4) + i4];                                         \
    uint4 w3 = WL4[((s << 4) + i4) * 256 + q];                             \
    DOT2BF(a0, w0_##i4.x, hh.x); DOT2BF(a0, w0_##i4.y, hh.y);              \
    DOT2BF(a0, w0_##i4.z, hh.z); DOT2BF(a0, w0_##i4.w, hh.w);              \
    DOT2BF(a1, w1_##i4.x, hh.x); DOT2BF(a1, w1_##i4.y, hh.y);              \
    DOT2BF(a1, w1_##i4.z, hh.z); DOT2BF(a1, w1_##i4.w, hh.w);              \
    DOT2BF(a2, w2_##i4.x, hh.x); DOT2BF(a2, w2_##i4.y, hh.y);              \
    DOT2BF(a2, w2_##i4.z, hh.z); DOT2BF(a2, w2_##i4.w, hh.w);              \
    DOT2BF(a3, w3.x, hh.x); DOT2BF(a3, w3.y, hh.y);                        \
    DOT2BF(a3, w3.z, hh.z); DOT2BF(a3, w3.w, hh.w);                        \
  }

__global__ void
__attribute__((amdgpu_flat_work_group_size(512, 512), amdgpu_waves_per_eu(2, 2)))
lstm_kernel(const unsigned* __restrict__ Wreg,
            const unsigned* __restrict__ WLg,
            const float* __restrict__ lstmTh,
            const float* __restrict__ xw,
            float* __restrict__ hb) {
  extern __shared__ char smem[];
  unsigned* WL = (unsigned*)smem;               // [32][256] uint4 rows (131072 B)
  float* part = (float*)(smem + 131072);        // [8][256]  (g*2+s, q)
  float* qv = part + 2048;                      // [1024]  segment-scan values, gate-major
  float* wtot = qv + 1024;                      // [16]  (wave, slot)
  unsigned* hp = (unsigned*)(wtot + 16);        // [128] packed bf16 h pairs

  const int t = threadIdx.x;
  const int b = blockIdx.x;
  const int q = t & 255;
  const int s = t >> 8;
  const int lane = t & 63;
  const int w = t >> 6;  // wave 0..7

  {
    const uint4* src = (const uint4*)WLg;
    uint4* dst = (uint4*)WL;
    for (int j = t; j < 8192; j += 512) dst[j] = src[j];
  }
  const uint4* Wreg4 = (const uint4*)Wreg;
  uint4 w0_0, w0_1, w0_2, w0_3, w0_4, w0_5, w0_6, w0_7;
  uint4 w0_8, w0_9, w0_10, w0_11, w0_12, w0_13, w0_14, w0_15;
  uint4 w1_0, w1_1, w1_2, w1_3, w1_4, w1_5, w1_6, w1_7;
  uint4 w1_8, w1_9, w1_10, w1_11, w1_12, w1_13, w1_14, w1_15;
  uint4 w2_0, w2_1, w2_2, w2_3, w2_4, w2_5, w2_6, w2_7;
  uint4 w2_8, w2_9, w2_10, w2_11, w2_12, w2_13, w2_14, w2_15;
  LOADW(0)
  LOADW(1)
  LOADW(2)
  const float thA = lstmTh[t];          // gate s, col q
  const float thB = lstmTh[512 + t];    // gate s+2, col q
  float cx = 0.f;                       // valid for t<256 (q-owner)
  if (t < 128) hp[t] = 0u;
  __syncthreads();

  const int xbase = (b << 8) * 1024;
  const uint4* WL4 = (const uint4*)WL;
  const uint4* hp4 = (const uint4*)hp;

  float xa = xw[xbase + t];
  float xb = xw[xbase + 512 + t];

  for (int st = 0; st < 256; ++st) {
    // prefetch next step's xw (consumed next iteration; hides HBM latency)
    int nx = (st < 255) ? st + 1 : 255;
    float xa_n = xw[xbase + nx * 1024 + t];
    float xb_n = xw[xbase + nx * 1024 + 512 + t];

    // ---- GEMV half-dots: 4 gates, 128 d each (64 pairs = 16 chunks) ----
    float a0 = 0.f, a1 = 0.f, a2 = 0.f, a3 = 0.f;
    CHUNK(0) CHUNK(1) CHUNK(2) CHUNK(3)
    CHUNK(4) CHUNK(5) CHUNK(6) CHUNK(7)
    CHUNK(8) CHUNK(9) CHUNK(10) CHUNK(11)
    CHUNK(12) CHUNK(13) CHUNK(14) CHUNK(15)
    part[(0 * 2 + s) * 256 + q] = a0;
    part[(1 * 2 + s) * 256 + q] = a1;
    part[(2 * 2 + s) * 256 + q] = a2;
    part[(3 * 2 + s) * 256 + q] = a3;
    __syncthreads();  // barrier 1: partials ready

    // ---- finalize z; cos; segment scan (wave = one 64-col segment) ----
    int gA = s, gB = s + 2;
    float zA = part[(gA * 2 + 0) * 256 + q] + part[(gA * 2 + 1) * 256 + q] + xa + thA;
    float zB = part[(gB * 2 + 0) * 256 + q] + part[(gB * 2 + 1) * 256 + q] + xb + thB;
    float vA = __cosf(zA);
    float vB = __cosf(zB);
#pragma unroll
    for (int off = 1; off < 64; off <<= 1) {
      float oA = __shfl_up(vA, off, 64);
      float oB = __shfl_up(vB, off, 64);
      if (lane >= off) { vA *= oA; vB *= oB; }
    }
    if (lane == 63) { wtot[w * 2] = vA; wtot[w * 2 + 1] = vB; }
    qv[s * 256 + q] = vA;        // gate s     (segment-local scan)
    qv[512 + s * 256 + q] = vB;  // gate s+2
    __syncthreads();  // barrier 2: qv + wtot ready

    // ---- combine (threads 0..255 own column q); apply segment prefixes here ----
    if (t < 256) {
      int j = q >> 6;  // segment index == wave-within-gate, uniform per wave
      float p0 = 1.f, p1 = 1.f, p2 = 1.f, p3 = 1.f;
      for (int k = 0; k < j; ++k) {
        p0 *= wtot[2 * k];            // gate0: slot A, waves 0..3
        p1 *= wtot[2 * (4 + k)];      // gate1: slot A, waves 4..7
        p2 *= wtot[2 * k + 1];        // gate2: slot B, waves 0..3
        p3 *= wtot[2 * (4 + k) + 1];  // gate3: slot B, waves 4..7
      }
      float fg = sigm(qv[t] * p0);
      float ig = sigm(qv[256 + t] * p1);
      float gg = tanh_f(qv[512 + t] * p2);
      float og = sigm(qv[768 + t] * p3);
      cx = fg * cx + ig * gg;
      float hv = og * tanh_f(cx);
      hb[((b << 8) + st) * 256 + t] = hv;
      float nb = __shfl_xor(hv, 1, 64);
      if ((t & 1) == 0) hp[t >> 1] = (unsigned)f2bf(hv) | ((unsigned)f2bf(nb) << 16);
    }
    __syncthreads();  // barrier 3: hp ready
    xa = xa_n;
    xb = xb_n;
  }
}

// ---------------- h += sinusoidal PE ----------------
__global__ void pe_add_kernel(float* __restrict__ h) {
  int tok = blockIdx.x, tid = threadIdx.x;
  int s = tok & 255;
  int j = tid >> 1;
  float div = __expf((float)j * -0.07195578415622253f);
  float ang = (float)s * div;
  float pe = (tid & 1) ? __cosf(ang) : __sinf(ang);
  h[tok * 256 + tid] += pe;
}

// ---------------- qproj x3 fused (f32 out, contiguous q/k/v buffers) ----------------
__global__ void qproj3_kernel(const float* __restrict__ hin, const float* __restrict__ thetas,
                              float* __restrict__ outbase) {
  __shared__ float wtot[4];
  int tok = blockIdx.x, y = blockIdx.y;
  int tid = threadIdx.x, lane = tid & 63, wid = tid >> 6;
  const float* theta = thetas + y * 256;
  float* out = outbase + (long)y * 1048576;
  float v = __cosf(hin[tok * 256 + tid] + theta[tid]);
#pragma unroll
  for (int off = 1; off < 64; off <<= 1) {
    float o = __shfl_up(v, off, 64);
    if (lane >= off) v *= o;
  }
  if (lane == 63) wtot[wid] = v;
  __syncthreads();
  float pre = 1.f;
  for (int w = 0; w < wid; ++w) pre *= wtot[w];
  out[tok * 256 + tid] = v * pre;
}

// ---------------- qproj -> bf16 (FFN input) ----------------
__global__ void qproj_bf_kernel(const float* __restrict__ hin, const float* __restrict__ theta,
                                unsigned short* __restrict__ outb) {
  __shared__ float wtot[4];
  int tok = blockIdx.x, tid = threadIdx.x, lane = tid & 63, wid = tid >> 6;
  float v = __cosf(hin[tok * 256 + tid] + theta[tid]);
#pragma unroll
  for (int off = 1; off < 64; off <<= 1) {
    float o = __shfl_up(v, off, 64);
    if (lane >= off) v *= o;
  }
  if (lane == 63) wtot[wid] = v;
  __syncthreads();
  float pre = 1.f;
  for (int w = 0; w < wid; ++w) pre *= wtot[w];
  outb[tok * 256 + tid] = f2bf(v * pre);
}

// ---------------- attention: block per (head,batch); vectorized LDS ----------------
// Q,K at stride 36 (float4-aligned); V staged d-major [32][260] so PV is float4.
__global__ void __launch_bounds__(256, 1) attn_kernel(const float* __restrict__ qb,
                                                      const float* __restrict__ kb,
                                                      const float* __restrict__ vb,
                                                      unsigned short* __restrict__ outb) {
  extern __shared__ float sm[];
  float* Qs = sm;                 // [256][36]
  float* Ks = Qs + 256 * 36;      // [256][36]
  float* Vs = Ks + 256 * 36;      // [32][260]  d-major
  float* ps = Vs + 32 * 260;      // [4][256]
  int hd = blockIdx.x, b = blockIdx.y;
  int tid = threadIdx.x, lane = tid & 63, wid = tid >> 6;
  const float scale = 0.17677669529663687f;  // 1/sqrt(32)

  for (int i = tid; i < 256 * 32; i += 256) {
    int r = i >> 5, d = i & 31;
    int src = (b * 256 + r) * 256 + hd * 32 + d;
    Qs[r * 36 + d] = qb[src];
    Ks[r * 36 + d] = kb[src];
    Vs[d * 260 + r] = vb[src];
  }
  __syncthreads();

  float* pw = ps + wid * 256;
  for (int r = wid; r < 256; r += 4) {
    float4 qreg[8];
    const float4* qrow = (const float4*)(Qs + r * 36);
#pragma unroll
    for (int i = 0; i < 8; ++i) qreg[i] = qrow[i];
    float s[4];
#pragma unroll
    for (int j = 0; j < 4; ++j) {
      int k = lane + 64 * j;
      const float4* kr = (const float4*)(Ks + k * 36);
      float a = 0.f;
#pragma unroll
      for (int i = 0; i < 8; ++i) {
        float4 kv = kr[i];
        a += qreg[i].x * kv.x + qreg[i].y * kv.y + qreg[i].z * kv.z + qreg[i].w * kv.w;
      }
      s[j] = a * scale;
    }
    float m = fmaxf(fmaxf(s[0], s[1]), fmaxf(s[2], s[3]));
#pragma unroll
    for (int off = 32; off; off >>= 1) m = fmaxf(m, __shfl_xor(m, off, 64));
    float p[4], sum = 0.f;
#pragma unroll
    for (int j = 0; j < 4; ++j) { p[j] = __expf(s[j] - m); sum += p[j]; }
#pragma unroll
    for (int off = 32; off; off >>= 1) sum += __shfl_xor(sum, off, 64);
    float inv = rcp_f(sum);
#pragma unroll
    for (int j = 0; j < 4; ++j) pw[lane + 64 * j] = p[j] * inv;
    int d = lane & 31, half = lane >> 5;
    const float4* pv = (const float4*)(pw + half * 128);
    const float4* v4 = (const float4*)(Vs + d * 260 + half * 128);
    float a = 0.f;
#pragma unroll
    for (int i = 0; i < 32; ++i) {
      float4 pp = pv[i];
      float4 vv = v4[i];
      a += pp.x * vv.x + pp.y * vv.y + pp.z * vv.z + pp.w * vv.w;
    }
    a += __shfl_down(a, 32, 64);
    if (lane < 32) outb[(b * 256 + r) * 256 + hd * 32 + d] = f2bf(a);
  }
}

// ---------------- layernorm(h + delta) -> h ----------------
__global__ void ln_kernel(float* __restrict__ hio, const float* __restrict__ delta,
                          const float* __restrict__ gamma, const float* __restrict__ beta) {
  __shared__ float red[16];
  int tok = blockIdx.x, tid = threadIdx.x, lane = tid & 63, wid = tid >> 6;
  float v = hio[tok * 256 + tid] + delta[tok * 256 + tid];
  float s1 = v, s2 = v * v;
#pragma unroll
  for (int off = 32; off; off >>= 1) {
    s1 += __shfl_xor(s1, off, 64);
    s2 += __shfl_xor(s2, off, 64);
  }
  if (lane == 0) { red[wid] = s1; red[wid + 8] = s2; }
  __syncthreads();
  float t1 = red[0] + red[1] + red[2] + red[3];
  float t2 = red[8] + red[9] + red[10] + red[11];
  float mean = t1 * (1.f / 256.f);
  float var = t2 * (1.f / 256.f) - mean * mean;
  float w = rsqrtf(var + 1e-5f);
  hio[tok * 256 + tid] = (v - mean) * w * gamma[tid] + beta[tid];
}

// ---------------- mean pool over S + classifier ----------------
__global__ void pool_cls_kernel(const float* __restrict__ h, const float* __restrict__ clsW,
                                const float* __restrict__ clsb, float* __restrict__ out) {
  __shared__ float pl[256];
  __shared__ float red[8];
  int b = blockIdx.x, tid = threadIdx.x, lane = tid & 63, wid = tid >> 6;
  float s = 0.f;
  for (int t = 0; t < 256; ++t) s += h[(b * 256 + t) * 256 + tid];
  pl[tid] = s * (1.f / 256.f);
  __syncthreads();
  for (int c = 0; c < 4; ++c) {
    float v = pl[tid] * clsW[tid * 4 + c];
#pragma unroll
    for (int off = 32; off; off >>= 1) v += __shfl_xor(v, off, 64);
    if (lane == 0) red[wid] = v;
    __syncthreads();
    if (tid == 0) out[b * 4 + c] = red[0] + red[1] + red[2] + red[3] + clsb[c];
    __syncthreads();
  }
}

extern "C" void kernel_launch(void* const* d_in, const int* in_sizes, int n_in,
                              void* d_out, int out_size, void* d_ws, size_t ws_size,
                              hipStream_t stream) {
  const int* x = (const int*)d_in[0];
  const float* token_emb = (const float*)d_in[1];
  const float* lstm_W = (const float*)d_in[2];
  const float* lstm_b = (const float*)d_in[3];
  const float* lstm_th = (const float*)d_in[4];
  const float* ln1_g = (const float*)d_in[5];
  const float* ln1_b = (const float*)d_in[6];
  const float* ln2_g = (const float*)d_in[7];
  const float* ln2_b = (const float*)d_in[8];
  const float* qkv_th = (const float*)d_in[9];
  const float* comb_W = (const float*)d_in[10];
  const float* comb_b = (const float*)d_in[11];
  const float* ffn_th = (const float*)d_in[12];
  const float* lin1_W = (const float*)d_in[13];
  const float* lin1_b = (const float*)d_in[14];
  const float* lin2_W = (const float*)d_in[15];
  const float* lin2_b = (const float*)d_in[16];
  const float* cls_W = (const float*)d_in[17];
  const float* cls_b = (const float*)d_in[18];

  float* ws = (float*)d_ws;
  typedef unsigned short ushort_t;
  ushort_t* emb_b = (ushort_t*)ws;       // 1M f32 region: emb bf16 pre-loop / attn bf16 in-loop
  ushort_t* att_b = emb_b;
  float* xw = ws + 1048576;              // 4M f32: xw pre-loop / ffh bf16 in-loop
  ushort_t* ffh_b = (ushort_t*)xw;
  float* hb = ws + 5242880;   // 1M
  float* qq = ws + 6291456;   // 1M  (qq,kk,vv contiguous for fused qproj3)
  float* kk = ws + 7340032;   // 1M
  float* vv = ws + 8388608;   // 1M
  float* tmp = ws + 9437184;  // 1M; first 131072 u32 reused pre-loop for lstm packs
  unsigned* Wreg = (unsigned*)tmp;            // 98304 uints
  unsigned* WLg = (unsigned*)(tmp + 98304);   // 32768 uints
  ushort_t* ffq_b = (ushort_t*)(ws + 10485760);  // 1M ushort
  ushort_t* wxt_b = (ushort_t*)(ws + 11534336);  // 262144 (4 gates x [256][256])
  ushort_t* cmb_b = wxt_b + 262144;              // 2 x 65536
  ushort_t* l1_b = cmb_b + 131072;               // 2 x 262144
  ushort_t* l2_b = l1_b + 524288;                // 2 x 262144

  const int LSTM_LDS = 131072 + 8192 + 4096 + 64 + 512;            // 143936 B
  const int ATT_LDS = (256 * 36 * 2 + 32 * 260 + 4 * 256) * 4;     // 111104 B
  (void)hipFuncSetAttribute(reinterpret_cast<const void*>(lstm_kernel),
                            hipFuncAttributeMaxDynamicSharedMemorySize, LSTM_LDS);
  (void)hipFuncSetAttribute(reinterpret_cast<const void*>(attn_kernel),
                            hipFuncAttributeMaxDynamicSharedMemorySize, ATT_LDS);

  embed_kernel<<<4096, 256, 0, stream>>>(x, token_emb, emb_b);
  pack_wreg_kernel<<<384, 256, 0, stream>>>(lstm_W, Wreg);
  pack_wl_kernel<<<128, 256, 0, stream>>>(lstm_W, WLg);
  pack_bt<<<dim3(4, 4, 4), 256, 0, stream>>>(lstm_W, 256, 256, wxt_b, 131072, 65536);
  pack_bt<<<dim3(4, 4, 2), 256, 0, stream>>>(comb_W, 256, 256, cmb_b, 65536, 65536);
  pack_bt<<<dim3(16, 4, 2), 256, 0, stream>>>(lin1_W, 256, 1024, l1_b, 262144, 262144);
  pack_bt<<<dim3(4, 16, 2), 256, 0, stream>>>(lin2_W, 1024, 256, l2_b, 262144, 262144);

  // xw = emb @ Wx + lstm_b : M=4096 N=1024 K=256
  gemm_mfma<<<dim3(8, 32), 256, 0, stream>>>(emb_b, wxt_b, lstm_b,
                                             xw, nullptr, 4096, 1024, 256, 0);
  lstm_kernel<<<16, 512, LSTM_LDS, stream>>>(Wreg, WLg, lstm_th, xw, hb);
  pe_add_kernel<<<4096, 256, 0, stream>>>(hb);

  for (int l = 0; l < 2; ++l) {
    qproj3_kernel<<<dim3(4096, 3), 256, 0, stream>>>(hb, qkv_th + l * 768, qq);
    attn_kernel<<<dim3(8, 16), 256, ATT_LDS, stream>>>(qq, kk, vv, att_b);
    gemm_mfma<<<dim3(2, 32), 256, 0, stream>>>(att_b, cmb_b + l * 65536, comb_b + l * 256,
                                               tmp, nullptr, 4096, 256, 256, 0);
    ln_kernel<<<4096, 256, 0, stream>>>(hb, tmp, ln1_g + l * 256, ln1_b + l * 256);
    qproj_bf_kernel<<<4096, 256, 0, stream>>>(hb, ffn_th + l * 256, ffq_b);
    gemm_mfma<<<dim3(8, 32), 256, 0, stream>>>(ffq_b, l1_b + l * 262144, lin1_b + l * 1024,
                                               nullptr, ffh_b, 4096, 1024, 256, 1);
    gemm_mfma<<<dim3(2, 32), 256, 0, stream>>>(ffh_b, l2_b + l * 262144, lin2_b + l * 256,
                                               tmp, nullptr, 4096, 256, 1024, 0);
    ln_kernel<<<4096, 256, 0, stream>>>(hb, tmp, ln2_g + l * 256, ln2_b + l * 256);
  }

  pool_cls_kernel<<<16, 256, 0, stream>>>(hb, cls_W, cls_b, (float*)d_out);
}

// Round 8
// 1191.551 us; speedup vs baseline: 3.5231x; 1.0300x over previous
//
#include <hip/hip_runtime.h>
#include <hip/hip_bf16.h>

// Problem constants: B=16, S=256, V=32000, E=256, H=8, L=2, FFN=1024, NC=4, DK=32, NQ=256

typedef __attribute__((ext_vector_type(8))) short bf8v;   // 8 bf16 in 4 VGPRs
typedef __attribute__((ext_vector_type(4))) float f4v;    // MFMA accumulator
#define MFMA16 __builtin_amdgcn_mfma_f32_16x16x32_bf16

__device__ __forceinline__ unsigned short f2bf(float f) {
  unsigned u = __builtin_bit_cast(unsigned, f);
  u += 0x7fffu + ((u >> 16) & 1u);
  return (unsigned short)(u >> 16);
}
__device__ __forceinline__ float rcp_f(float x) { return __builtin_amdgcn_rcpf(x); }
__device__ __forceinline__ float sigm(float x) { return rcp_f(1.f + __expf(-x)); }
__device__ __forceinline__ float tanh_f(float x) { return 1.f - 2.f * rcp_f(__expf(2.f * x) + 1.f); }

// v_dot2_f32_bf16: acc += a.x*b.x + a.y*b.y  (packed bf16 pairs in uint)
#define DOT2BF(acc, a, b) \
  asm("v_dot2_f32_bf16 %0, %1, %2, %0" : "+v"(acc) : "v"(a), "v"(b))

// ---------------- embedding gather -> bf16 ----------------
__global__ void embed_kernel(const int* __restrict__ x, const float* __restrict__ tab,
                             unsigned short* __restrict__ eb) {
  int tok = blockIdx.x, tid = threadIdx.x;
  eb[tok * 256 + tid] = f2bf(tab[x[tok] * 256 + tid]);
}

// ---- transpose to bf16: W [K][N] f32 -> T[n][k] bf16 ; blockIdx.z batches slices ----
__global__ void pack_bt(const float* __restrict__ W, int K, int N,
                        unsigned short* __restrict__ Th, long wz, long tz) {
  __shared__ float tile[64][65];
  W += (long)blockIdx.z * wz;
  Th += (long)blockIdx.z * tz;
  int n0 = blockIdx.x * 64, k0 = blockIdx.y * 64;
  int tid = threadIdx.x, tx = tid & 63, ty = tid >> 6;
  for (int r = ty; r < 64; r += 4) tile[r][tx] = W[(k0 + r) * N + n0 + tx];
  __syncthreads();
  for (int r = ty; r < 64; r += 4) {
    Th[(n0 + r) * K + k0 + tx] = f2bf(tile[tx][r]);  // = W[k0+tx][n0+r]
  }
}

// ---- pack h-part of gate (blockIdx.y) as bf16 d-pairs, uint4-friendly LDS layout ----
// uint o = (p4*256 + q)*4 + c ; pair p = p4*4+c, d = 2p
__global__ void pack_wl_kernel(const float* __restrict__ lstmW, unsigned* __restrict__ WLg) {
  int gate = blockIdx.y;
  int o = blockIdx.x * 256 + threadIdx.x;  // < 32768
  int c = o & 3;
  int q = (o >> 2) & 255;
  int p4 = o >> 10;  // 0..31
  int d = 2 * (p4 * 4 + c);
  unsigned lo = f2bf(lstmW[(gate * 512 + 256 + d) * 256 + q]);
  unsigned hi = f2bf(lstmW[(gate * 512 + 256 + d + 1) * 256 + q]);
  WLg[gate * 32768 + o] = lo | (hi << 16);
}

// ---------------- MFMA GEMM, single-pass bf16: C = A*B + bias ----------------
__global__ void __launch_bounds__(256) gemm_mfma(const unsigned short* __restrict__ A,
                                                 const unsigned short* __restrict__ B,
                                                 const float* __restrict__ bias,
                                                 float* __restrict__ Cf,
                                                 unsigned short* __restrict__ Cb,
                                                 int M, int N, int K, int mode) {
  __shared__ unsigned short As[128 * 40];
  __shared__ unsigned short Bs[128 * 40];

  const int tid = threadIdx.x;
  const int lane = tid & 63;
  const int wid = tid >> 6;
  const int wr = wid >> 1, wc = wid & 1;
  const int bm = blockIdx.y * 128, bn = blockIdx.x * 128;

  const int srow = tid >> 2;
  const int scol = (tid & 3) * 8;

  f4v acc[4][4] = {};

  for (int kt = 0; kt < K; kt += 32) {
#pragma unroll
    for (int p = 0; p < 2; ++p) {
      int r = srow + p * 64;
      *(uint4*)(&As[r * 40 + scol]) = *(const uint4*)(&A[(bm + r) * K + kt + scol]);
      *(uint4*)(&Bs[r * 40 + scol]) = *(const uint4*)(&B[(bn + r) * K + kt + scol]);
    }
    __syncthreads();

    bf8v a[4], b[4];
    const int kq = (lane >> 4) * 8;
#pragma unroll
    for (int f = 0; f < 4; ++f) {
      a[f] = *(const bf8v*)(&As[(wr * 64 + f * 16 + (lane & 15)) * 40 + kq]);
      b[f] = *(const bf8v*)(&Bs[(wc * 64 + f * 16 + (lane & 15)) * 40 + kq]);
    }
#pragma unroll
    for (int fm = 0; fm < 4; ++fm)
#pragma unroll
      for (int fn = 0; fn < 4; ++fn)
        acc[fm][fn] = MFMA16(a[fm], b[fn], acc[fm][fn], 0, 0, 0);
    __syncthreads();
  }

#pragma unroll
  for (int fm = 0; fm < 4; ++fm)
#pragma unroll
    for (int fn = 0; fn < 4; ++fn) {
      int c = bn + wc * 64 + fn * 16 + (lane & 15);
      int r0 = bm + wr * 64 + fm * 16 + ((lane >> 4) << 2);
      float bv = bias[c];
#pragma unroll
      for (int j = 0; j < 4; ++j) {
        float v = acc[fm][fn][j] + bv;
        if (mode == 1) {
          Cb[(r0 + j) * N + c] = f2bf(fmaxf(v, 0.f));
        } else {
          Cf[(r0 + j) * N + c] = v;
        }
      }
    }
}

// ---------------- QLSTM: 64 blocks = (batch, gate); weights fully LDS-resident ------------
// 512 threads: q = t&255, s = t>>8 (d-half). Gate g's Wh [256][256] bf16 packed in LDS.
// Cross-gate exchange via tagged 64-bit relaxed agent atomics (value<<32 | step+1),
// double-buffered by step parity. Each block computes cx/h REDUNDANTLY (bitwise-identical)
// so the exchange is one-way: publish own gate, poll+read other three.
__global__ void __launch_bounds__(512)
lstm_kernel(const unsigned* __restrict__ WLgAll,
            const float* __restrict__ lstmTh,
            const float* __restrict__ xw,
            float* __restrict__ hb,
            unsigned long long* __restrict__ qex) {
  extern __shared__ char smem[];
  unsigned* WL = (unsigned*)smem;               // [32][256] uint4 rows (131072 B)
  float* part = (float*)(smem + 131072);        // [2][256]
  float* wtot = part + 512;                     // [4] (+4 pad)
  unsigned* hp = (unsigned*)(wtot + 8);         // [128] packed bf16 h pairs (16B aligned)

  const int t = threadIdx.x;
  const int b = blockIdx.x >> 2;
  const int g = blockIdx.x & 3;
  const int q = t & 255;
  const int s = t >> 8;
  const int lane = t & 63;
  const int w = t >> 6;  // wave 0..7; scan uses waves 0..3

  {
    const uint4* src = (const uint4*)WLgAll + g * 8192;
    uint4* dst = (uint4*)WL;
    for (int j = t; j < 8192; j += 512) dst[j] = src[j];
  }
  const float th = lstmTh[g * 256 + q];
  float cx = 0.f;  // replicated per (b,q); valid for t<256
  if (t < 128) hp[t] = 0u;
  __syncthreads();

  const uint4* WL4 = (const uint4*)WL;
  const uint4* hp4 = (const uint4*)hp;
  const int xrow = (b << 8) * 1024 + g * 256 + q;

  for (int st = 0; st < 256; ++st) {
    float xv = xw[xrow + st * 1024];

    // ---- GEMV half-dot for own gate: 128 d = 64 pairs = 16 uint4 (all LDS) ----
    float acc = 0.f;
#pragma unroll
    for (int i4 = 0; i4 < 16; ++i4) {
      uint4 hh = hp4[(s << 4) + i4];              // wave-uniform -> broadcast
      uint4 wv = WL4[((s << 4) + i4) * 256 + q];  // consecutive b128
      DOT2BF(acc, wv.x, hh.x); DOT2BF(acc, wv.y, hh.y);
      DOT2BF(acc, wv.z, hh.z); DOT2BF(acc, wv.w, hh.w);
    }
    part[s * 256 + q] = acc;
    __syncthreads();  // bar1: partials ready

    float v = 0.f;
    if (t < 256) {
      float z = part[q] + part[256 + q] + xv + th;
      v = __cosf(z);
#pragma unroll
      for (int off = 1; off < 64; off <<= 1) {
        float o = __shfl_up(v, off, 64);
        if (lane >= off) v *= o;
      }
      if (lane == 63) wtot[w] = v;
    }
    __syncthreads();  // bar2: wtot ready

    if (t < 256) {
      {
        float p = 1.f;
        int j = q >> 6;
        for (int k = 0; k < j; ++k) p *= wtot[k];
        v *= p;
      }
      // ---- publish own gate value (tag-in-data, parity-buffered) ----
      const unsigned tag = (unsigned)(st + 1);
      const int par = st & 1;
      unsigned long long pk =
          ((unsigned long long)__builtin_bit_cast(unsigned, v) << 32) | tag;
      __hip_atomic_store(&qex[(((par * 16 + b) * 4 + g) << 8) + q], pk,
                         __ATOMIC_RELAXED, __HIP_MEMORY_SCOPE_AGENT);
      // ---- gather all four gate values (own local; others polled) ----
      float q0v = 0.f, q1v = 0.f, q2v = 0.f, q3v = 0.f;
#pragma unroll
      for (int gg = 0; gg < 4; ++gg) {
        float val;
        if (gg == g) {
          val = v;
        } else {
          unsigned long long got;
          for (;;) {
            got = __hip_atomic_load(&qex[(((par * 16 + b) * 4 + gg) << 8) + q],
                                    __ATOMIC_RELAXED, __HIP_MEMORY_SCOPE_AGENT);
            if ((unsigned)got == tag) break;
            __builtin_amdgcn_s_sleep(1);
          }
          val = __builtin_bit_cast(float, (unsigned)(got >> 32));
        }
        if (gg == 0) q0v = val;
        else if (gg == 1) q1v = val;
        else if (gg == 2) q2v = val;
        else q3v = val;
      }
      // ---- replicated combine: identical fp sequence in all 4 blocks ----
      float fg = sigm(q0v);
      float ig = sigm(q1v);
      float gg_ = tanh_f(q2v);
      float og = sigm(q3v);
      cx = fg * cx + ig * gg_;
      float hv = og * tanh_f(cx);
      if (g == 0) hb[((b << 8) + st) * 256 + q] = hv;
      float nb = __shfl_xor(hv, 1, 64);
      if ((t & 1) == 0) hp[t >> 1] = (unsigned)f2bf(hv) | ((unsigned)f2bf(nb) << 16);
    }
    __syncthreads();  // bar3: hp ready for next step
  }
}

// ---------------- h += sinusoidal PE ----------------
__global__ void pe_add_kernel(float* __restrict__ h) {
  int tok = blockIdx.x, tid = threadIdx.x;
  int s = tok & 255;
  int j = tid >> 1;
  float div = __expf((float)j * -0.07195578415622253f);
  float ang = (float)s * div;
  float pe = (tid & 1) ? __cosf(ang) : __sinf(ang);
  h[tok * 256 + tid] += pe;
}

// ---------------- qproj x3 fused (f32 out, contiguous q/k/v buffers) ----------------
__global__ void qproj3_kernel(const float* __restrict__ hin, const float* __restrict__ thetas,
                              float* __restrict__ outbase) {
  __shared__ float wtot[4];
  int tok = blockIdx.x, y = blockIdx.y;
  int tid = threadIdx.x, lane = tid & 63, wid = tid >> 6;
  const float* theta = thetas + y * 256;
  float* out = outbase + (long)y * 1048576;
  float v = __cosf(hin[tok * 256 + tid] + theta[tid]);
#pragma unroll
  for (int off = 1; off < 64; off <<= 1) {
    float o = __shfl_up(v, off, 64);
    if (lane >= off) v *= o;
  }
  if (lane == 63) wtot[wid] = v;
  __syncthreads();
  float pre = 1.f;
  for (int w = 0; w < wid; ++w) pre *= wtot[w];
  out[tok * 256 + tid] = v * pre;
}

// ---------------- fused layernorm(h+delta)->h  +  qproj->bf16 (FFN input) ----------------
__global__ void ln_qproj_kernel(float* __restrict__ hio, const float* __restrict__ delta,
                                const float* __restrict__ gamma, const float* __restrict__ beta,
                                const float* __restrict__ theta,
                                unsigned short* __restrict__ outb) {
  __shared__ float red[16];
  __shared__ float wtot[4];
  int tok = blockIdx.x, tid = threadIdx.x, lane = tid & 63, wid = tid >> 6;
  float v = hio[tok * 256 + tid] + delta[tok * 256 + tid];
  float s1 = v, s2 = v * v;
#pragma unroll
  for (int off = 32; off; off >>= 1) {
    s1 += __shfl_xor(s1, off, 64);
    s2 += __shfl_xor(s2, off, 64);
  }
  if (lane == 0) { red[wid] = s1; red[wid + 8] = s2; }
  __syncthreads();
  float t1 = red[0] + red[1] + red[2] + red[3];
  float t2 = red[8] + red[9] + red[10] + red[11];
  float mean = t1 * (1.f / 256.f);
  float var = t2 * (1.f / 256.f) - mean * mean;
  float w = rsqrtf(var + 1e-5f);
  float val = (v - mean) * w * gamma[tid] + beta[tid];
  hio[tok * 256 + tid] = val;
  // qproj on the freshly-normalized value (no global round-trip)
  float c = __cosf(val + theta[tid]);
#pragma unroll
  for (int off = 1; off < 64; off <<= 1) {
    float o = __shfl_up(c, off, 64);
    if (lane >= off) c *= o;
  }
  if (lane == 63) wtot[wid] = c;
  __syncthreads();
  float pre = 1.f;
  for (int k = 0; k < wid; ++k) pre *= wtot[k];
  outb[tok * 256 + tid] = f2bf(c * pre);
}

// ---------------- attention: block per (head,batch); vectorized LDS ----------------
__global__ void __launch_bounds__(256, 1) attn_kernel(const float* __restrict__ qb,
                                                      const float* __restrict__ kb,
                                                      const float* __restrict__ vb,
                                                      unsigned short* __restrict__ outb) {
  extern __shared__ float sm[];
  float* Qs = sm;                 // [256][36]
  float* Ks = Qs + 256 * 36;      // [256][36]
  float* Vs = Ks + 256 * 36;      // [32][260]  d-major
  float* ps = Vs + 32 * 260;      // [4][256]
  int hd = blockIdx.x, b = blockIdx.y;
  int tid = threadIdx.x, lane = tid & 63, wid = tid >> 6;
  const float scale = 0.17677669529663687f;  // 1/sqrt(32)

  for (int i = tid; i < 256 * 32; i += 256) {
    int r = i >> 5, d = i & 31;
    int src = (b * 256 + r) * 256 + hd * 32 + d;
    Qs[r * 36 + d] = qb[src];
    Ks[r * 36 + d] = kb[src];
    Vs[d * 260 + r] = vb[src];
  }
  __syncthreads();

  float* pw = ps + wid * 256;
  for (int r = wid; r < 256; r += 4) {
    float4 qreg[8];
    const float4* qrow = (const float4*)(Qs + r * 36);
#pragma unroll
    for (int i = 0; i < 8; ++i) qreg[i] = qrow[i];
    float s[4];
#pragma unroll
    for (int j = 0; j < 4; ++j) {
      int k = lane + 64 * j;
      const float4* kr = (const float4*)(Ks + k * 36);
      float a = 0.f;
#pragma unroll
      for (int i = 0; i < 8; ++i) {
        float4 kv = kr[i];
        a += qreg[i].x * kv.x + qreg[i].y * kv.y + qreg[i].z * kv.z + qreg[i].w * kv.w;
      }
      s[j] = a * scale;
    }
    float m = fmaxf(fmaxf(s[0], s[1]), fmaxf(s[2], s[3]));
#pragma unroll
    for (int off = 32; off; off >>= 1) m = fmaxf(m, __shfl_xor(m, off, 64));
    float p[4], sum = 0.f;
#pragma unroll
    for (int j = 0; j < 4; ++j) { p[j] = __expf(s[j] - m); sum += p[j]; }
#pragma unroll
    for (int off = 32; off; off >>= 1) sum += __shfl_xor(sum, off, 64);
    float inv = rcp_f(sum);
#pragma unroll
    for (int j = 0; j < 4; ++j) pw[lane + 64 * j] = p[j] * inv;
    int d = lane & 31, half = lane >> 5;
    const float4* pv = (const float4*)(pw + half * 128);
    const float4* v4 = (const float4*)(Vs + d * 260 + half * 128);
    float a = 0.f;
#pragma unroll
    for (int i = 0; i < 32; ++i) {
      float4 pp = pv[i];
      float4 vv = v4[i];
      a += pp.x * vv.x + pp.y * vv.y + pp.z * vv.z + pp.w * vv.w;
    }
    a += __shfl_down(a, 32, 64);
    if (lane < 32) outb[(b * 256 + r) * 256 + hd * 32 + d] = f2bf(a);
  }
}

// ---------------- layernorm(h + delta) -> h ----------------
__global__ void ln_kernel(float* __restrict__ hio, const float* __restrict__ delta,
                          const float* __restrict__ gamma, const float* __restrict__ beta) {
  __shared__ float red[16];
  int tok = blockIdx.x, tid = threadIdx.x, lane = tid & 63, wid = tid >> 6;
  float v = hio[tok * 256 + tid] + delta[tok * 256 + tid];
  float s1 = v, s2 = v * v;
#pragma unroll
  for (int off = 32; off; off >>= 1) {
    s1 += __shfl_xor(s1, off, 64);
    s2 += __shfl_xor(s2, off, 64);
  }
  if (lane == 0) { red[wid] = s1; red[wid + 8] = s2; }
  __syncthreads();
  float t1 = red[0] + red[1] + red[2] + red[3];
  float t2 = red[8] + red[9] + red[10] + red[11];
  float mean = t1 * (1.f / 256.f);
  float var = t2 * (1.f / 256.f) - mean * mean;
  float w = rsqrtf(var + 1e-5f);
  hio[tok * 256 + tid] = (v - mean) * w * gamma[tid] + beta[tid];
}

// ---------------- mean pool over S + classifier ----------------
__global__ void pool_cls_kernel(const float* __restrict__ h, const float* __restrict__ clsW,
                                const float* __restrict__ clsb, float* __restrict__ out) {
  __shared__ float pl[256];
  __shared__ float red[8];
  int b = blockIdx.x, tid = threadIdx.x, lane = tid & 63, wid = tid >> 6;
  float s = 0.f;
  for (int t = 0; t < 256; ++t) s += h[(b * 256 + t) * 256 + tid];
  pl[tid] = s * (1.f / 256.f);
  __syncthreads();
  for (int c = 0; c < 4; ++c) {
    float v = pl[tid] * clsW[tid * 4 + c];
#pragma unroll
    for (int off = 32; off; off >>= 1) v += __shfl_xor(v, off, 64);
    if (lane == 0) red[wid] = v;
    __syncthreads();
    if (tid == 0) out[b * 4 + c] = red[0] + red[1] + red[2] + red[3] + clsb[c];
    __syncthreads();
  }
}

extern "C" void kernel_launch(void* const* d_in, const int* in_sizes, int n_in,
                              void* d_out, int out_size, void* d_ws, size_t ws_size,
                              hipStream_t stream) {
  const int* x = (const int*)d_in[0];
  const float* token_emb = (const float*)d_in[1];
  const float* lstm_W = (const float*)d_in[2];
  const float* lstm_b = (const float*)d_in[3];
  const float* lstm_th = (const float*)d_in[4];
  const float* ln1_g = (const float*)d_in[5];
  const float* ln1_b = (const float*)d_in[6];
  const float* ln2_g = (const float*)d_in[7];
  const float* ln2_b = (const float*)d_in[8];
  const float* qkv_th = (const float*)d_in[9];
  const float* comb_W = (const float*)d_in[10];
  const float* comb_b = (const float*)d_in[11];
  const float* ffn_th = (const float*)d_in[12];
  const float* lin1_W = (const float*)d_in[13];
  const float* lin1_b = (const float*)d_in[14];
  const float* lin2_W = (const float*)d_in[15];
  const float* lin2_b = (const float*)d_in[16];
  const float* cls_W = (const float*)d_in[17];
  const float* cls_b = (const float*)d_in[18];

  float* ws = (float*)d_ws;
  typedef unsigned short ushort_t;
  ushort_t* emb_b = (ushort_t*)ws;       // 1M f32 region: emb bf16 pre-loop / attn bf16 in-loop
  ushort_t* att_b = emb_b;
  float* xw = ws + 1048576;              // 4M f32: xw pre-loop / ffh bf16 in-loop
  ushort_t* ffh_b = (ushort_t*)xw;
  float* hb = ws + 5242880;   // 1M
  float* qq = ws + 6291456;   // 1M  (qq,kk,vv contiguous for fused qproj3)
  float* kk = ws + 7340032;   // 1M
  float* vv = ws + 8388608;   // 1M
  float* tmp = ws + 9437184;  // 1M; first 131072 u32 reused pre-loop for lstm weight pack
  unsigned* WLg = (unsigned*)tmp;                // 4 x 32768 uints (all gates)
  ushort_t* ffq_b = (ushort_t*)(ws + 10485760);  // 1M ushort
  ushort_t* wxt_b = (ushort_t*)(ws + 11534336);  // 262144 (4 gates x [256][256])
  ushort_t* cmb_b = wxt_b + 262144;              // 2 x 65536
  ushort_t* l1_b = cmb_b + 131072;               // 2 x 262144
  ushort_t* l2_b = l1_b + 524288;                // 2 x 262144  (ends at f32 idx 12255232)
  unsigned long long* qex = (unsigned long long*)(ws + 12255232);  // 2*16*4*256 u64 = 256 KB

  const int LSTM_LDS = 131072 + 2048 + 32 + 512;                   // 133664 B
  const int ATT_LDS = (256 * 36 * 2 + 32 * 260 + 4 * 256) * 4;     // 111104 B
  (void)hipFuncSetAttribute(reinterpret_cast<const void*>(lstm_kernel),
                            hipFuncAttributeMaxDynamicSharedMemorySize, LSTM_LDS);
  (void)hipFuncSetAttribute(reinterpret_cast<const void*>(attn_kernel),
                            hipFuncAttributeMaxDynamicSharedMemorySize, ATT_LDS);

  // tags must start invalid every launch (poison is fine, but be explicit)
  hipMemsetAsync(qex, 0, 2 * 16 * 4 * 256 * 8, stream);

  embed_kernel<<<4096, 256, 0, stream>>>(x, token_emb, emb_b);
  pack_wl_kernel<<<dim3(128, 4), 256, 0, stream>>>(lstm_W, WLg);
  pack_bt<<<dim3(4, 4, 4), 256, 0, stream>>>(lstm_W, 256, 256, wxt_b, 131072, 65536);
  pack_bt<<<dim3(4, 4, 2), 256, 0, stream>>>(comb_W, 256, 256, cmb_b, 65536, 65536);
  pack_bt<<<dim3(16, 4, 2), 256, 0, stream>>>(lin1_W, 256, 1024, l1_b, 262144, 262144);
  pack_bt<<<dim3(4, 16, 2), 256, 0, stream>>>(lin2_W, 1024, 256, l2_b, 262144, 262144);

  // xw = emb @ Wx + lstm_b : M=4096 N=1024 K=256
  gemm_mfma<<<dim3(8, 32), 256, 0, stream>>>(emb_b, wxt_b, lstm_b,
                                             xw, nullptr, 4096, 1024, 256, 0);
  lstm_kernel<<<64, 512, LSTM_LDS, stream>>>(WLg, lstm_th, xw, hb, qex);
  pe_add_kernel<<<4096, 256, 0, stream>>>(hb);

  for (int l = 0; l < 2; ++l) {
    qproj3_kernel<<<dim3(4096, 3), 256, 0, stream>>>(hb, qkv_th + l * 768, qq);
    attn_kernel<<<dim3(8, 16), 256, ATT_LDS, stream>>>(qq, kk, vv, att_b);
    gemm_mfma<<<dim3(2, 32), 256, 0, stream>>>(att_b, cmb_b + l * 65536, comb_b + l * 256,
                                               tmp, nullptr, 4096, 256, 256, 0);
    ln_qproj_kernel<<<4096, 256, 0, stream>>>(hb, tmp, ln1_g + l * 256, ln1_b + l * 256,
                                              ffn_th + l * 256, ffq_b);
    gemm_mfma<<<dim3(8, 32), 256, 0, stream>>>(ffq_b, l1_b + l * 262144, lin1_b + l * 1024,
                                               nullptr, ffh_b, 4096, 1024, 256, 1);
    gemm_mfma<<<dim3(2, 32), 256, 0, stream>>>(ffh_b, l2_b + l * 262144, lin2_b + l * 256,
                                               tmp, nullptr, 4096, 256, 1024, 0);
    ln_kernel<<<4096, 256, 0, stream>>>(hb, tmp, ln2_g + l * 256, ln2_b + l * 256);
  }

  pool_cls_kernel<<<16, 256, 0, stream>>>(hb, cls_W, cls_b, (float*)d_out);
}